// Round 8
// baseline (281.904 us; speedup 1.0000x reference)
//
#include <hip/hip_runtime.h>
#include <stdint.h>

#define TT 2048
#define HH 16
#define LOG2E 1.44269504089f

typedef _Float16 f16;
typedef __attribute__((ext_vector_type(8))) _Float16 f16x8;
typedef __attribute__((ext_vector_type(4))) _Float16 f16x4;
typedef __attribute__((ext_vector_type(4))) float f32x4;
typedef unsigned short ushort_t;

// async global->LDS, 16B per lane (GEMM only)
__device__ __forceinline__ void gl_lds16(const void* g, void* l){
  __builtin_amdgcn_global_load_lds(
      (__attribute__((address_space(1))) void*)(void*)g,
      (__attribute__((address_space(3))) void*)l, 16, 0, 0);
}

// barrier WITHOUT vmcnt drain: LDS ops done, but global loads stay in flight
__device__ __forceinline__ void lds_barrier(){
  __asm__ volatile("s_waitcnt lgkmcnt(0)\n\ts_barrier" ::: "memory");
}

// ---------------- block schedule (chunk = 8 k-tiles), LPT order ----------------
struct SchedT { unsigned short v[80]; };
static constexpr SchedT make_sched(){
  SchedT s{};
  int idx = 0;
  for (int size = 8; size >= 1; --size){
    for (int qt = 31; qt >= 8; --qt){
      int full = qt >> 3;
      int tail = (qt & 7) + 1;
      if (size == 8)
        for (int ci = 0; ci < full; ++ci)
          s.v[idx++] = (unsigned short)(qt | (ci << 8));
      if (tail == size)
        s.v[idx++] = (unsigned short)(qt | (full << 8));
    }
    s.v[idx++] = (unsigned short)(size - 1);
  }
  return s;
}
__constant__ SchedT SCHED = make_sched();

// prefix of partial-slot count: slots for qt' in [8, qt)
__device__ __forceinline__ int slot_base(int qt){
  return (qt < 16) ? 2 * (qt - 8)
       : (qt < 24) ? 16 + 3 * (qt - 16)
                   : 40 + 4 * (qt - 24);
}

// ---------------- convert x: f32 -> f16 ----------------
__global__ __launch_bounds__(256) void cvt_f2h_kernel(const float4* __restrict__ in,
                                                      uint2* __restrict__ out, int n4){
  int i = blockIdx.x * 256 + threadIdx.x;
  if (i >= n4) return;
  float4 v = in[i];
  union { f16 h[4]; uint2 u; } o;
  o.h[0] = (f16)v.x; o.h[1] = (f16)v.y; o.h[2] = (f16)v.z; o.h[3] = (f16)v.w;
  out[i] = o.u;
}

// ---------------- pack bias: lower-triangle 64x64 tiles, TRANSPOSED frag order ----
// Consumer (swapped-QK^T attn): thread t'=(q>>4)*64 + ((k>>2)&3)*16 + (q&15),
// word j=(k>>4)*4 + (k&3) holds element (q, k): u32 = f16(gadj) | etype<<16.
// This order makes producer writes contiguous uint4 per (row, v4) pair.
__global__ __launch_bounds__(256) void pack_bias_kernel(const float* __restrict__ gadj,
                                                        const int* __restrict__ etype,
                                                        uint32_t* __restrict__ out){
  int bid = blockIdx.x;
  int b = bid / 528, ti = bid - b * 528;
  int qt = (int)((sqrtf(8.f * (float)ti + 1.f) - 1.f) * 0.5f);
  while ((qt + 1) * (qt + 2) / 2 <= ti) ++qt;
  while (qt * (qt + 1) / 2 > ti) --qt;
  int kt = ti - qt * (qt + 1) / 2;

  int t = threadIdx.x;
  int row = t >> 2, c0 = (t & 3) << 4;     // reads row, cols c0..c0+15
  size_t src = ((size_t)b * TT + qt * 64 + row) * TT + kt * 64 + c0;
  uint32_t* dst = out + (size_t)bid * 4096;
  int wq = (row >> 4) * 64 + (row & 15);
  #pragma unroll
  for (int v4 = 0; v4 < 4; ++v4){
    float4 g = *(const float4*)(gadj + src + v4 * 4);
    int4   e = *(const int4*)(etype + src + v4 * 4);
    union { f16 h; ushort_t u; } c;
    uint4 o;
    c.h = (f16)g.x; o.x = (uint32_t)c.u | ((uint32_t)e.x << 16);
    c.h = (f16)g.y; o.y = (uint32_t)c.u | ((uint32_t)e.y << 16);
    c.h = (f16)g.z; o.z = (uint32_t)c.u | ((uint32_t)e.z << 16);
    c.h = (f16)g.w; o.w = (uint32_t)c.u | ((uint32_t)e.w << 16);
    *(uint4*)(dst + (((size_t)(wq + v4 * 16)) << 4) + ((t & 3) << 2)) = o;
  }
}

// ---------------- transpose+convert: f32 [R][C] -> f16 [C][R] ----------------
__global__ __launch_bounds__(256) void transpose_cvt_kernel(const float* __restrict__ in,
                                                            f16* __restrict__ out, int R, int C){
  __shared__ float tile[64][65];
  int c0 = blockIdx.x * 64, r0 = blockIdx.y * 64;
  int t = threadIdx.x;
  int row = t >> 2, cs = (t & 3) << 4;
  const float4* src = (const float4*)(in + (size_t)(r0 + row) * C + c0 + cs);
  float4 a = src[0], b = src[1], c = src[2], d = src[3];
  float* tr = &tile[row][cs];
  tr[0]=a.x; tr[1]=a.y; tr[2]=a.z;  tr[3]=a.w;
  tr[4]=b.x; tr[5]=b.y; tr[6]=b.z;  tr[7]=b.w;
  tr[8]=c.x; tr[9]=c.y; tr[10]=c.z; tr[11]=c.w;
  tr[12]=d.x;tr[13]=d.y;tr[14]=d.z; tr[15]=d.w;
  __syncthreads();
  f16 tmp[16];
  #pragma unroll
  for (int j = 0; j < 16; ++j) tmp[j] = (f16)tile[cs + j][row];
  f16* dst = out + (size_t)(c0 + row) * R + r0 + cs;
  *(uint4*)dst = *(uint4*)&tmp[0];
  *(uint4*)(dst + 8) = *(uint4*)&tmp[8];
}

// ---------------- GEMM: C[M][N] = A[M][K] @ Bt[N][K]^T, tile 128 x BN ----------------
template<int BN>
__global__ __launch_bounds__(256) void gemm_f16_kernel(const f16* __restrict__ A,
                                                       const f16* __restrict__ Bt,
                                                       void* __restrict__ Cout,
                                                       int M, int N, int K, int out_f32){
  constexpr int WN = BN / 2;
  constexpr int NI = WN / 16;
  __shared__ __align__(16) f16 As[128 * 32];
  __shared__ __align__(16) f16 Bs[BN * 32];
  int t = threadIdx.x;
  int w = t >> 6, lane = t & 63;
  int wm = (w >> 1) * 64, wn = (w & 1) * WN;
  int lrow = lane & 15, quad = lane >> 4;
  int bm = blockIdx.y, bn = blockIdx.x;

  f32x4 acc[4][NI];
  for (int i = 0; i < 4; ++i)
    for (int j = 0; j < NI; ++j)
      for (int r = 0; r < 4; ++r) acc[i][j][r] = 0.f;

  const int nk = K >> 5;
  for (int kt = 0; kt < nk; ++kt){
    int k0 = kt << 5;
    __syncthreads();
    #pragma unroll
    for (int i = 0; i < 2; ++i){
      int c = (w << 7) + (i << 6) + lane;
      gl_lds16(A + (size_t)((bm << 7) + (c >> 2)) * K + k0 + ((c & 3) << 3),
               As + ((w << 7) + (i << 6)) * 8);
      if constexpr (BN == 128){
        gl_lds16(Bt + (size_t)((bn << 7) + (c >> 2)) * K + k0 + ((c & 3) << 3),
                 Bs + ((w << 7) + (i << 6)) * 8);
      }
    }
    if constexpr (BN == 64){
      int c = (w << 6) + lane;
      gl_lds16(Bt + (size_t)((bn << 6) + (c >> 2)) * K + k0 + ((c & 3) << 3),
               Bs + (w << 6) * 8);
    }
    __syncthreads();
    f16x8 af[4], bfr[NI];
    #pragma unroll
    for (int mi = 0; mi < 4; ++mi)
      af[mi] = *(const f16x8*)(As + (wm + mi * 16 + lrow) * 32 + quad * 8);
    #pragma unroll
    for (int ni = 0; ni < NI; ++ni)
      bfr[ni] = *(const f16x8*)(Bs + (wn + ni * 16 + lrow) * 32 + quad * 8);
    #pragma unroll
    for (int mi = 0; mi < 4; ++mi)
      #pragma unroll
      for (int ni = 0; ni < NI; ++ni)
        acc[mi][ni] = __builtin_amdgcn_mfma_f32_16x16x32_f16(af[mi], bfr[ni], acc[mi][ni], 0, 0, 0);
  }

  #pragma unroll
  for (int mi = 0; mi < 4; ++mi)
    #pragma unroll
    for (int ni = 0; ni < NI; ++ni)
      #pragma unroll
      for (int r = 0; r < 4; ++r){
        int row = (bm << 7) + wm + mi * 16 + quad * 4 + r;
        int col = bn * BN + wn + ni * 16 + lrow;
        float val = acc[mi][ni][r];
        if (out_f32) ((float*)Cout)[(size_t)row * N + col] = val;
        else         ((f16*)Cout)[(size_t)row * N + col] = (f16)val;
      }
}

// ---------------- fused causal graph attention: swapped QK^T, register-resident P ----
// S^T = mfma(K,Q) puts scores lane-local (q=lrow, k=nb*16+quad*4+r) -> softmax is
// in-lane + 2 shfl; P feeds chained mfma_16x16x16 PV directly (A-layout match).
// No P LDS round-trip; Ps buffer deleted (LDS ~20.6 KB).
__global__ __launch_bounds__(256, 4) void attn_kernel(const f16* __restrict__ qkv,
                                                      const uint32_t* __restrict__ pbias,
                                                      const float* __restrict__ adj_bias,
                                                      const float* __restrict__ edge_table,
                                                      f16* __restrict__ attn_out,
                                                      f16* __restrict__ Opart,
                                                      float* __restrict__ MLpart){
  __shared__ __align__(16) f16 Ks[64 * 72];
  __shared__ __align__(16) f16 Vt[64 * 72];   // transposed [hd][key], xor-swizzled 16B blocks
  __shared__ float edge_lds[32 * 17];         // 32 replicas, stride 17

  int bx = blockIdx.x;
  int bh = bx & 31;
  int h = bh & 15, b = bh >> 4;
  int ej = SCHED.v[bx >> 5];
  int qt = ej & 31, ci = ej >> 8;
  int ksrt = ci << 3;
  int kend = min(qt, ksrt + 7);
  bool whole = (qt < 8);

  int t = threadIdx.x;
  int w = t >> 6, lane = t & 63;
  int lrow = lane & 15, quad = lane >> 4;

  for (int i = t; i < 544; i += 256)
    edge_lds[i] = edge_table[(i % 17) * HH + h] * LOG2E;
  float adjb = adj_bias[h] * LOG2E;
  int erep = (lane & 31) * 17;

  int q0 = qt * 64 + w * 16;
  const size_t qrow = ((size_t)b * TT + q0 + lrow) * 3072 + h * 64;
  f16x8 qf0 = *(const f16x8*)(qkv + qrow + quad * 8);
  f16x8 qf1 = *(const f16x8*)(qkv + qrow + 32 + quad * 8);

  f32x4 o[4];
  for (int i = 0; i < 4; ++i)
    for (int r = 0; r < 4; ++r) o[i][r] = 0.f;
  float mrun = -1e30f, lrun = 0.f;   // this lane's q = q0 + lrow

  // staging geometry: thread handles keys (keyA, keyA+1) x hd segment hdA..hdA+7
  const int keyA = (t >> 3) << 1;
  const int hdA  = (t & 7) << 3;
  const int sA   = ((keyA >> 3) ^ (hdA >> 3)) & 7;
  const f16* kbase = qkv + (size_t)b * TT * 3072 + 1024 + h * 64;
  const f16* vbase = qkv + (size_t)b * TT * 3072 + 2048 + h * 64;
  const size_t koffA = (size_t)keyA * 3072 + hdA;
  const size_t koffB = koffA + 3072;

  const float SCL = 0.125f * LOG2E;

  const int tribase = b * 528 + ((qt * (qt + 1)) >> 1);
  const uint32_t* bthread = pbias + ((size_t)t << 4);
  const int qg = q0 + lrow;          // this lane's global q row

  // ---- prefetch first tile's K/V
  uint4 ka, kb, va, vb;
  {
    const f16* kr = kbase + (size_t)(ksrt * 64) * 3072;
    const f16* vr = vbase + (size_t)(ksrt * 64) * 3072;
    ka = *(const uint4*)(kr + koffA); kb = *(const uint4*)(kr + koffB);
    va = *(const uint4*)(vr + koffA); vb = *(const uint4*)(vr + koffB);
  }

  for (int kt2 = ksrt; kt2 <= kend; ++kt2){
    lds_barrier();
    // ---- bias loads for CUR tile (consumed at mask step)
    union B4 { uint4 v; uint32_t e[4]; } bb0, bb1, bb2, bb3;
    {
      const uint32_t* tp = bthread + ((size_t)(tribase + kt2) << 12);
      bb0.v = *(const uint4*)(tp + 0);
      bb1.v = *(const uint4*)(tp + 4);
      bb2.v = *(const uint4*)(tp + 8);
      bb3.v = *(const uint4*)(tp + 12);
    }
    // ---- LDS writes from prefetched regs
    *(uint4*)(Ks + keyA * 72 + hdA) = ka;
    *(uint4*)(Ks + (keyA + 1) * 72 + hdA) = kb;
    {
      union { uint4 u; f16 hh[8]; } ua, ub;
      ua.u = va; ub.u = vb;
      #pragma unroll
      for (int jj = 0; jj < 8; ++jj){
        union { f16 h[2]; uint32_t wv; } pr;
        pr.h[0] = ua.hh[jj]; pr.h[1] = ub.hh[jj];
        *(uint32_t*)(Vt + (hdA + jj) * 72 + (sA << 3) + (keyA & 7)) = pr.wv;
      }
    }
    // ---- issue NEXT tile's K/V
    if (kt2 < kend){
      const f16* kr = kbase + (size_t)((kt2 + 1) * 64) * 3072;
      const f16* vr = vbase + (size_t)((kt2 + 1) * 64) * 3072;
      ka = *(const uint4*)(kr + koffA); kb = *(const uint4*)(kr + koffB);
      va = *(const uint4*)(vr + koffA); vb = *(const uint4*)(vr + koffB);
    }
    lds_barrier();

    // ---- S^T = K Q^T  (swapped operands; D: col=lrow=q, row=quad*4+r=k_local)
    f32x4 sf[4];
    #pragma unroll
    for (int nb = 0; nb < 4; ++nb){
      f32x4 s = {0.f, 0.f, 0.f, 0.f};
      f16x8 kf0 = *(const f16x8*)(Ks + (nb * 16 + lrow) * 72 + quad * 8);
      f16x8 kf1 = *(const f16x8*)(Ks + (nb * 16 + lrow) * 72 + 32 + quad * 8);
      s = __builtin_amdgcn_mfma_f32_16x16x32_f16(kf0, qf0, s, 0, 0, 0);
      s = __builtin_amdgcn_mfma_f32_16x16x32_f16(kf1, qf1, s, 0, 0, 0);
      sf[nb] = s;
    }

    // ---- bias + causal mask: lane holds (q=qg, k = kt2*64 + nb*16 + quad*4 + r)
    int kq = kt2 * 64 + quad * 4;
    float sarr[4][4];
    bool diag = (kt2 == qt);
#define MASK_NB(nb, BB)                                                          \
    {                                                                            \
      _Pragma("unroll")                                                          \
      for (int r = 0; r < 4; ++r){                                               \
        float v;                                                                 \
        if (diag && (kq + nb * 16 + r > qg)) v = -1e30f;                         \
        else {                                                                   \
          uint32_t bp = BB.e[r];                                                 \
          union { ushort_t u; f16 h; } cv; cv.u = (ushort_t)bp;                  \
          v = sf[nb][r] * SCL + adjb * (float)cv.h + edge_lds[erep + (bp >> 16)];\
        }                                                                        \
        sarr[nb][r] = v;                                                         \
      }                                                                          \
    }
    MASK_NB(0, bb0)
    MASK_NB(1, bb1)
    MASK_NB(2, bb2)
    MASK_NB(3, bb3)
#undef MASK_NB

    // ---- online softmax: in-lane over 16 + cross-quad shfl (lanes l, l^16, l^32, l^48)
    float m_ = -1e30f;
    #pragma unroll
    for (int nb = 0; nb < 4; ++nb)
      #pragma unroll
      for (int r = 0; r < 4; ++r)
        m_ = fmaxf(m_, sarr[nb][r]);
    m_ = fmaxf(m_, __shfl_xor(m_, 16));
    m_ = fmaxf(m_, __shfl_xor(m_, 32));
    bool need = (m_ > mrun + 5.0f);
    if (__any(need)){
      float mnew = fmaxf(mrun, m_);
      float alpha = exp2f(mrun - mnew);
      lrun *= alpha;
      #pragma unroll
      for (int r = 0; r < 4; ++r){
        float ar = __shfl(alpha, (quad << 2) | r);   // alpha for q_local = quad*4+r
        #pragma unroll
        for (int nbh = 0; nbh < 4; ++nbh) o[nbh][r] *= ar;
      }
      mrun = mnew;
    }
    float rs = 0.f;
    #pragma unroll
    for (int nb = 0; nb < 4; ++nb)
      #pragma unroll
      for (int r = 0; r < 4; ++r){
        float p = exp2f(sarr[nb][r] - mrun);
        sarr[nb][r] = p; rs += p;
      }
    rs += __shfl_xor(rs, 16);
    rs += __shfl_xor(rs, 32);
    lrun += rs;

    // ---- pack P into mfma16 A-frags (layout match: row=lrow=q, k=quad*4+j)
    f16x4 pa[4];
    #pragma unroll
    for (int nb = 0; nb < 4; ++nb){
      pa[nb][0] = (f16)sarr[nb][0];
      pa[nb][1] = (f16)sarr[nb][1];
      pa[nb][2] = (f16)sarr[nb][2];
      pa[nb][3] = (f16)sarr[nb][3];
    }

    // ---- O += P V : chained 16x16x16 MFMAs, Vt b64 fragments (swizzled)
    #pragma unroll
    for (int nb = 0; nb < 4; ++nb){
      #pragma unroll
      for (int nbh = 0; nbh < 4; ++nbh){
        int hd = nbh * 16 + lrow;
        int s2 = ((nb * 2 + (quad >> 1)) ^ (hd >> 3)) & 7;
        f16x4 vf = *(const f16x4*)(Vt + hd * 72 + (s2 << 3) + ((quad & 1) << 2));
        o[nbh] = __builtin_amdgcn_mfma_f32_16x16x16f16(pa[nb], vf, o[nbh], 0, 0, 0);
      }
    }
  }

  if (whole){
    #pragma unroll
    for (int r = 0; r < 4; ++r){
      float inv = 1.0f / __shfl(lrun, (quad << 2) | r);
      int qg2 = q0 + quad * 4 + r;
      #pragma unroll
      for (int nbh = 0; nbh < 4; ++nbh){
        int col = h * 64 + nbh * 16 + lrow;
        attn_out[((size_t)b * TT + qg2) * 1024 + col] = (f16)(o[nbh][r] * inv);
      }
    }
  } else {
    int slot = bh * 72 + slot_base(qt) + ci;
    f16* Ob = Opart + (size_t)slot * 4096;
    #pragma unroll
    for (int nbh = 0; nbh < 4; ++nbh)
      #pragma unroll
      for (int r = 0; r < 4; ++r)
        Ob[(w * 16 + quad * 4 + r) * 64 + nbh * 16 + lrow] = (f16)o[nbh][r];
    if (quad == 0){
      MLpart[(size_t)slot * 128 + w * 16 + lrow] = mrun;
      MLpart[(size_t)slot * 128 + 64 + w * 16 + lrow] = lrun;
    }
  }
}

// ---------------- combine 2..4 partial chunks for qt>=8 ----------------
__global__ __launch_bounds__(256) void combine_kernel(const f16* __restrict__ Opart,
                                                      const float* __restrict__ ML,
                                                      f16* __restrict__ attn_out){
  int qt = blockIdx.x + 8;          // 8..31
  int bh = blockIdx.y;              // 0..31
  int nch = (qt >> 3) + 1;          // 2..4
  int slot0 = bh * 72 + slot_base(qt);
  int t = threadIdx.x;
  int q = t >> 2;
  int hd0 = (t & 3) << 4;

  float m[4], l[4];
  float M = -1e30f;
  #pragma unroll
  for (int c = 0; c < 4; ++c){
    if (c < nch){
      m[c] = ML[(size_t)(slot0 + c) * 128 + q];
      l[c] = ML[(size_t)(slot0 + c) * 128 + 64 + q];
      M = fmaxf(M, m[c]);
    } else { m[c] = -1e30f; l[c] = 0.f; }
  }
  float acc[16];
  #pragma unroll
  for (int i = 0; i < 16; ++i) acc[i] = 0.f;
  float L = 0.f;
  #pragma unroll
  for (int c = 0; c < 4; ++c){
    if (c < nch){
      float wgt = exp2f(m[c] - M);
      L += l[c] * wgt;
      const f16* O = Opart + (size_t)(slot0 + c) * 4096 + q * 64 + hd0;
      f16x8 a0 = *(const f16x8*)O, a1 = *(const f16x8*)(O + 8);
      #pragma unroll
      for (int i = 0; i < 8; ++i){
        acc[i]     += (float)a0[i] * wgt;
        acc[i + 8] += (float)a1[i] * wgt;
      }
    }
  }
  float invL = 1.0f / L;
  f16 outv[16];
  #pragma unroll
  for (int i = 0; i < 16; ++i) outv[i] = (f16)(acc[i] * invL);
  int b = bh >> 4, h = bh & 15;
  f16* dst = attn_out + ((size_t)b * TT + qt * 64 + q) * 1024 + h * 64 + hd0;
  *(uint4*)dst = *(uint4*)&outv[0];
  *(uint4*)(dst + 8) = *(uint4*)&outv[8];
}

extern "C" void kernel_launch(void* const* d_in, const int* in_sizes, int n_in,
                              void* d_out, int out_size, void* d_ws, size_t ws_size,
                              hipStream_t stream){
  (void)in_sizes; (void)n_in; (void)out_size; (void)ws_size;
  const float* x_f32  = (const float*)d_in[0];
  const float* gadj   = (const float*)d_in[1];
  const int*   etype  = (const int*)d_in[2];
  const float* wqkv   = (const float*)d_in[3];
  const float* wproj  = (const float*)d_in[4];
  const float* adjb   = (const float*)d_in[5];
  const float* etab   = (const float*)d_in[6];

  // workspace layout (peak ~72.3 MB):
  //  [0,8)    x_f16, reused as attn_out
  //  [8,32)   qkv
  //  [32,38)  wqkvT (dead after qkv GEMM) -- aliased by Opart [32,50.9)
  //  [51,53)  wprojT
  //  [53,54.2) MLpart
  //  [55,72.3) pbias (triangle-compressed u32 tiles, transposed fragment order)
  char* ws = (char*)d_ws;
  f16*     x_f16  = (f16*)(ws);
  f16*     qkv    = (f16*)(ws + (8u  << 20));
  f16*     wqkvT  = (f16*)(ws + (32u << 20));
  f16*     Opart  = (f16*)(ws + (32u << 20));
  f16*     wprojT = (f16*)(ws + (51u << 20));
  float*   MLpart = (float*)(ws + (53u << 20));
  uint32_t* pbias = (uint32_t*)(ws + (55u << 20));
  f16*     attn_o = x_f16;  // reuse

  cvt_f2h_kernel<<<4096, 256, 0, stream>>>((const float4*)x_f32, (uint2*)x_f16, 1048576);
  pack_bias_kernel<<<1056, 256, 0, stream>>>(gadj, etype, pbias);
  transpose_cvt_kernel<<<dim3(48, 16), 256, 0, stream>>>(wqkv, wqkvT, 1024, 3072);
  transpose_cvt_kernel<<<dim3(16, 16), 256, 0, stream>>>(wproj, wprojT, 1024, 1024);
  gemm_f16_kernel<128><<<dim3(24, 32), 256, 0, stream>>>(x_f16, wqkvT, qkv, 4096, 3072, 1024, 0);
  attn_kernel<<<2560, 256, 0, stream>>>(qkv, pbias, adjb, etab, attn_o, Opart, MLpart);
  combine_kernel<<<dim3(24, 32), 256, 0, stream>>>(Opart, MLpart, attn_o);
  gemm_f16_kernel<64><<<dim3(16, 32), 256, 0, stream>>>(attn_o, wprojT, d_out, 4096, 1024, 1024, 1);
}

// Round 9
// 281.009 us; speedup vs baseline: 1.0032x; 1.0032x over previous
//
#include <hip/hip_runtime.h>
#include <stdint.h>

#define TT 2048
#define HH 16
#define LOG2E 1.44269504089f

typedef _Float16 f16;
typedef __attribute__((ext_vector_type(8))) _Float16 f16x8;
typedef __attribute__((ext_vector_type(4))) _Float16 f16x4;
typedef __attribute__((ext_vector_type(4))) float f32x4;
typedef unsigned short ushort_t;

// async global->LDS, 16B per lane (GEMM only)
__device__ __forceinline__ void gl_lds16(const void* g, void* l){
  __builtin_amdgcn_global_load_lds(
      (__attribute__((address_space(1))) void*)(void*)g,
      (__attribute__((address_space(3))) void*)l, 16, 0, 0);
}

// barrier WITHOUT vmcnt drain: LDS ops done, but global loads stay in flight
__device__ __forceinline__ void lds_barrier(){
  __asm__ volatile("s_waitcnt lgkmcnt(0)\n\ts_barrier" ::: "memory");
}

// ---------------- block schedule: q-super-tiles of 128 rows, chunks of 8 k-tiles ----
// J in [0,16): covers k-tiles 0..2J+1 (NT = 2J+2). nch = ceil(NT/8). LPT order.
struct SchedT { unsigned short v[40]; };
static constexpr SchedT make_sched(){
  SchedT s{}; int idx = 0;
  for (int size = 8; size >= 1; --size)
    for (int J = 15; J >= 0; --J){
      int NT = 2 * J + 2;
      int f = NT >> 3, tail = NT - (f << 3);
      if (size == 8)
        for (int ci = 0; ci < f; ++ci) s.v[idx++] = (unsigned short)(J | (ci << 4));
      if (tail == size) s.v[idx++] = (unsigned short)(J | (f << 4));
    }
  return s;
}
__constant__ SchedT SCHED = make_sched();

// partial-slot prefix for J in [4,16): nch = 2 (J<8), 3 (J<12), 4 (J<16); total 36
__device__ __forceinline__ int slot_base(int J){
  return (J < 8) ? 2 * (J - 4)
       : (J < 12) ? 8 + 3 * (J - 8)
                  : 20 + 4 * (J - 12);
}

// ---------------- convert x: f32 -> f16 ----------------
__global__ __launch_bounds__(256) void cvt_f2h_kernel(const float4* __restrict__ in,
                                                      uint2* __restrict__ out, int n4){
  int i = blockIdx.x * 256 + threadIdx.x;
  if (i >= n4) return;
  float4 v = in[i];
  union { f16 h[4]; uint2 u; } o;
  o.h[0] = (f16)v.x; o.h[1] = (f16)v.y; o.h[2] = (f16)v.z; o.h[3] = (f16)v.w;
  out[i] = o.u;
}

// ---------------- pack bias: lower-triangle 64x64 tiles, TRANSPOSED frag order ----
// Consumer (swapped-QK^T attn): slot index = (q>>4)*64 + ((k>>2)&3)*16 + (q&15),
// word j=(k>>4)*4 + (k&3) holds element (q, k): u32 = f16(gadj) | etype<<16.
__global__ __launch_bounds__(256) void pack_bias_kernel(const float* __restrict__ gadj,
                                                        const int* __restrict__ etype,
                                                        uint32_t* __restrict__ out){
  int bid = blockIdx.x;
  int b = bid / 528, ti = bid - b * 528;
  int qt = (int)((sqrtf(8.f * (float)ti + 1.f) - 1.f) * 0.5f);
  while ((qt + 1) * (qt + 2) / 2 <= ti) ++qt;
  while (qt * (qt + 1) / 2 > ti) --qt;
  int kt = ti - qt * (qt + 1) / 2;

  int t = threadIdx.x;
  int row = t >> 2, c0 = (t & 3) << 4;     // reads row, cols c0..c0+15
  size_t src = ((size_t)b * TT + qt * 64 + row) * TT + kt * 64 + c0;
  uint32_t* dst = out + (size_t)bid * 4096;
  int wq = (row >> 4) * 64 + (row & 15);
  #pragma unroll
  for (int v4 = 0; v4 < 4; ++v4){
    float4 g = *(const float4*)(gadj + src + v4 * 4);
    int4   e = *(const int4*)(etype + src + v4 * 4);
    union { f16 h; ushort_t u; } c;
    uint4 o;
    c.h = (f16)g.x; o.x = (uint32_t)c.u | ((uint32_t)e.x << 16);
    c.h = (f16)g.y; o.y = (uint32_t)c.u | ((uint32_t)e.y << 16);
    c.h = (f16)g.z; o.z = (uint32_t)c.u | ((uint32_t)e.z << 16);
    c.h = (f16)g.w; o.w = (uint32_t)c.u | ((uint32_t)e.w << 16);
    *(uint4*)(dst + (((size_t)(wq + v4 * 16)) << 4) + ((t & 3) << 2)) = o;
  }
}

// ---------------- transpose+convert: f32 [R][C] -> f16 [C][R] ----------------
__global__ __launch_bounds__(256) void transpose_cvt_kernel(const float* __restrict__ in,
                                                            f16* __restrict__ out, int R, int C){
  __shared__ float tile[64][65];
  int c0 = blockIdx.x * 64, r0 = blockIdx.y * 64;
  int t = threadIdx.x;
  int row = t >> 2, cs = (t & 3) << 4;
  const float4* src = (const float4*)(in + (size_t)(r0 + row) * C + c0 + cs);
  float4 a = src[0], b = src[1], c = src[2], d = src[3];
  float* tr = &tile[row][cs];
  tr[0]=a.x; tr[1]=a.y; tr[2]=a.z;  tr[3]=a.w;
  tr[4]=b.x; tr[5]=b.y; tr[6]=b.z;  tr[7]=b.w;
  tr[8]=c.x; tr[9]=c.y; tr[10]=c.z; tr[11]=c.w;
  tr[12]=d.x;tr[13]=d.y;tr[14]=d.z; tr[15]=d.w;
  __syncthreads();
  f16 tmp[16];
  #pragma unroll
  for (int j = 0; j < 16; ++j) tmp[j] = (f16)tile[cs + j][row];
  f16* dst = out + (size_t)(c0 + row) * R + r0 + cs;
  *(uint4*)dst = *(uint4*)&tmp[0];
  *(uint4*)(dst + 8) = *(uint4*)&tmp[8];
}

// ---------------- GEMM: C[M][N] = A[M][K] @ Bt[N][K]^T, tile 128 x BN ----------------
template<int BN>
__global__ __launch_bounds__(256) void gemm_f16_kernel(const f16* __restrict__ A,
                                                       const f16* __restrict__ Bt,
                                                       void* __restrict__ Cout,
                                                       int M, int N, int K, int out_f32){
  constexpr int WN = BN / 2;
  constexpr int NI = WN / 16;
  __shared__ __align__(16) f16 As[128 * 32];
  __shared__ __align__(16) f16 Bs[BN * 32];
  int t = threadIdx.x;
  int w = t >> 6, lane = t & 63;
  int wm = (w >> 1) * 64, wn = (w & 1) * WN;
  int lrow = lane & 15, quad = lane >> 4;
  int bm = blockIdx.y, bn = blockIdx.x;

  f32x4 acc[4][NI];
  for (int i = 0; i < 4; ++i)
    for (int j = 0; j < NI; ++j)
      for (int r = 0; r < 4; ++r) acc[i][j][r] = 0.f;

  const int nk = K >> 5;
  for (int kt = 0; kt < nk; ++kt){
    int k0 = kt << 5;
    __syncthreads();
    #pragma unroll
    for (int i = 0; i < 2; ++i){
      int c = (w << 7) + (i << 6) + lane;
      gl_lds16(A + (size_t)((bm << 7) + (c >> 2)) * K + k0 + ((c & 3) << 3),
               As + ((w << 7) + (i << 6)) * 8);
      if constexpr (BN == 128){
        gl_lds16(Bt + (size_t)((bn << 7) + (c >> 2)) * K + k0 + ((c & 3) << 3),
                 Bs + ((w << 7) + (i << 6)) * 8);
      }
    }
    if constexpr (BN == 64){
      int c = (w << 6) + lane;
      gl_lds16(Bt + (size_t)((bn << 6) + (c >> 2)) * K + k0 + ((c & 3) << 3),
               Bs + (w << 6) * 8);
    }
    __syncthreads();
    f16x8 af[4], bfr[NI];
    #pragma unroll
    for (int mi = 0; mi < 4; ++mi)
      af[mi] = *(const f16x8*)(As + (wm + mi * 16 + lrow) * 32 + quad * 8);
    #pragma unroll
    for (int ni = 0; ni < NI; ++ni)
      bfr[ni] = *(const f16x8*)(Bs + (wn + ni * 16 + lrow) * 32 + quad * 8);
    #pragma unroll
    for (int mi = 0; mi < 4; ++mi)
      #pragma unroll
      for (int ni = 0; ni < NI; ++ni)
        acc[mi][ni] = __builtin_amdgcn_mfma_f32_16x16x32_f16(af[mi], bfr[ni], acc[mi][ni], 0, 0, 0);
  }

  #pragma unroll
  for (int mi = 0; mi < 4; ++mi)
    #pragma unroll
    for (int ni = 0; ni < NI; ++ni)
      #pragma unroll
      for (int r = 0; r < 4; ++r){
        int row = (bm << 7) + wm + mi * 16 + quad * 4 + r;
        int col = bn * BN + wn + ni * 16 + lrow;
        float val = acc[mi][ni][r];
        if (out_f32) ((float*)Cout)[(size_t)row * N + col] = val;
        else         ((f16*)Cout)[(size_t)row * N + col] = (f16)val;
      }
}

// ---------------- fused causal graph attention: 8 waves / 128 q-rows per block ----
// Swapped QK^T + register-resident P (R8 wave structure, unchanged per wave).
// Waves 0-3 -> q-tile 2J, waves 4-7 -> 2J+1; K/V staged once, shared by 8 waves.
// Staging roles: waves 0-3 stage V (paired-key b32), waves 4-7 stage K (b128).
__global__ __launch_bounds__(512, 4) void attn_kernel(const f16* __restrict__ qkv,
                                                      const uint32_t* __restrict__ pbias,
                                                      const float* __restrict__ adj_bias,
                                                      const float* __restrict__ edge_table,
                                                      f16* __restrict__ attn_out,
                                                      f16* __restrict__ Opart,
                                                      float* __restrict__ MLpart){
  __shared__ __align__(16) f16 Ks[64 * 72];
  __shared__ __align__(16) f16 Vt[64 * 72];   // transposed [hd][key], xor-swizzled 16B blocks
  __shared__ float edge_lds[32 * 17];         // 32 replicas, stride 17

  int bx = blockIdx.x;
  int bh = bx & 31;
  int h = bh & 15, b = bh >> 4;
  int ej = SCHED.v[bx >> 5];
  int J = ej & 15, ci = ej >> 4;
  int kts = ci << 3;
  int kend = min(2 * J + 1, kts + 7);
  bool whole = (J <= 3);

  int t = threadIdx.x;
  int w = t >> 6, lane = t & 63;
  int lrow = lane & 15, quad = lane >> 4;

  for (int i = t; i < 544; i += 512)
    edge_lds[i] = edge_table[(i % 17) * HH + h] * LOG2E;
  float adjb = adj_bias[h] * LOG2E;
  int erep = (lane & 31) * 17;

  const int qt_w = 2 * J + (w >> 2);         // this wave's diagonal k-tile
  const int q0 = J * 128 + w * 16;
  const size_t qrow = ((size_t)b * TT + q0 + lrow) * 3072 + h * 64;
  f16x8 qf0 = *(const f16x8*)(qkv + qrow + quad * 8);
  f16x8 qf1 = *(const f16x8*)(qkv + qrow + 32 + quad * 8);

  f32x4 o[4];
  for (int i = 0; i < 4; ++i)
    for (int r = 0; r < 4; ++r) o[i][r] = 0.f;
  float mrun = -1e30f, lrun = 0.f;   // this lane's q = q0 + lrow

  // staging roles (wave-uniform): t<256 -> V transpose, t>=256 -> K rows
  const bool vrole = (t < 256);
  const int vkeyA = (t >> 3) << 1;           // even key (V role)
  const int vhd   = (t & 7) << 3;
  const int vs    = ((vkeyA >> 3) ^ (vhd >> 3)) & 7;
  const int tt    = t - 256;                 // K role
  const int kkey  = tt >> 2;
  const int khd   = (tt & 3) << 4;
  const f16* kbase = qkv + (size_t)b * TT * 3072 + 1024 + h * 64;
  const f16* vbase = qkv + (size_t)b * TT * 3072 + 2048 + h * 64;

  const float SCL = 0.125f * LOG2E;

  const int tri_w = b * 528 + ((qt_w * (qt_w + 1)) >> 1);
  const uint32_t* bthread = pbias + ((size_t)(((w & 3) << 6) | lane) << 4);
  const int qg = q0 + lrow;                  // this lane's global q row

  // ---- prefetch first tile's K/V (role-split)
  uint4 ra, rb;
  if (vrole){
    const f16* vr = vbase + (size_t)(kts * 64) * 3072;
    ra = *(const uint4*)(vr + (size_t)vkeyA * 3072 + vhd);
    rb = *(const uint4*)(vr + (size_t)(vkeyA + 1) * 3072 + vhd);
  } else {
    const f16* kr = kbase + (size_t)(kts * 64) * 3072;
    ra = *(const uint4*)(kr + (size_t)kkey * 3072 + khd);
    rb = *(const uint4*)(kr + (size_t)kkey * 3072 + khd + 8);
  }

  for (int kt2 = kts; kt2 <= kend; ++kt2){
    bool act = (kt2 <= qt_w);
    lds_barrier();
    // ---- bias loads for CUR tile (active waves only)
    union B4 { uint4 v; uint32_t e[4]; } bb0, bb1, bb2, bb3;
    if (act){
      const uint32_t* tp = bthread + ((size_t)(tri_w + kt2) << 12);
      bb0.v = *(const uint4*)(tp + 0);
      bb1.v = *(const uint4*)(tp + 4);
      bb2.v = *(const uint4*)(tp + 8);
      bb3.v = *(const uint4*)(tp + 12);
    }
    // ---- LDS writes from prefetched regs (role-split)
    if (vrole){
      union { uint4 u; f16 hh[8]; } ua, ub;
      ua.u = ra; ub.u = rb;
      #pragma unroll
      for (int jj = 0; jj < 8; ++jj){
        union { f16 h[2]; uint32_t wv; } pr;
        pr.h[0] = ua.hh[jj]; pr.h[1] = ub.hh[jj];
        *(uint32_t*)(Vt + (vhd + jj) * 72 + (vs << 3) + (vkeyA & 7)) = pr.wv;
      }
    } else {
      *(uint4*)(Ks + kkey * 72 + khd) = ra;
      *(uint4*)(Ks + kkey * 72 + khd + 8) = rb;
    }
    // ---- issue NEXT tile's K/V
    if (kt2 < kend){
      if (vrole){
        const f16* vr = vbase + (size_t)((kt2 + 1) * 64) * 3072;
        ra = *(const uint4*)(vr + (size_t)vkeyA * 3072 + vhd);
        rb = *(const uint4*)(vr + (size_t)(vkeyA + 1) * 3072 + vhd);
      } else {
        const f16* kr = kbase + (size_t)((kt2 + 1) * 64) * 3072;
        ra = *(const uint4*)(kr + (size_t)kkey * 3072 + khd);
        rb = *(const uint4*)(kr + (size_t)kkey * 3072 + khd + 8);
      }
    }
    lds_barrier();

    if (act){
      // ---- S^T = K Q^T  (swapped operands; D: col=lrow=q, row=quad*4+r=k_local)
      f32x4 sf[4];
      #pragma unroll
      for (int nb = 0; nb < 4; ++nb){
        f32x4 s = {0.f, 0.f, 0.f, 0.f};
        f16x8 kf0 = *(const f16x8*)(Ks + (nb * 16 + lrow) * 72 + quad * 8);
        f16x8 kf1 = *(const f16x8*)(Ks + (nb * 16 + lrow) * 72 + 32 + quad * 8);
        s = __builtin_amdgcn_mfma_f32_16x16x32_f16(kf0, qf0, s, 0, 0, 0);
        s = __builtin_amdgcn_mfma_f32_16x16x32_f16(kf1, qf1, s, 0, 0, 0);
        sf[nb] = s;
      }

      // ---- bias + causal mask: lane holds (q=qg, k = kt2*64 + nb*16 + quad*4 + r)
      int kq = kt2 * 64 + quad * 4;
      float sarr[4][4];
      bool diag = (kt2 == qt_w);
#define MASK_NB(nb, BB)                                                          \
      {                                                                          \
        _Pragma("unroll")                                                        \
        for (int r = 0; r < 4; ++r){                                             \
          float v;                                                               \
          if (diag && (kq + nb * 16 + r > qg)) v = -1e30f;                       \
          else {                                                                 \
            uint32_t bp = BB.e[r];                                               \
            union { ushort_t u; f16 h; } cv; cv.u = (ushort_t)bp;                \
            v = sf[nb][r]*SCL + adjb*(float)cv.h + edge_lds[erep + (bp >> 16)];  \
          }                                                                      \
          sarr[nb][r] = v;                                                       \
        }                                                                        \
      }
      MASK_NB(0, bb0)
      MASK_NB(1, bb1)
      MASK_NB(2, bb2)
      MASK_NB(3, bb3)
#undef MASK_NB

      // ---- online softmax: in-lane over 16 + cross-quad shfl
      float m_ = -1e30f;
      #pragma unroll
      for (int nb = 0; nb < 4; ++nb)
        #pragma unroll
        for (int r = 0; r < 4; ++r)
          m_ = fmaxf(m_, sarr[nb][r]);
      m_ = fmaxf(m_, __shfl_xor(m_, 16));
      m_ = fmaxf(m_, __shfl_xor(m_, 32));
      bool need = (m_ > mrun + 5.0f);
      if (__any(need)){
        float mnew = fmaxf(mrun, m_);
        float alpha = exp2f(mrun - mnew);
        lrun *= alpha;
        #pragma unroll
        for (int r = 0; r < 4; ++r){
          float ar = __shfl(alpha, (quad << 2) | r);
          #pragma unroll
          for (int nbh = 0; nbh < 4; ++nbh) o[nbh][r] *= ar;
        }
        mrun = mnew;
      }
      float rs = 0.f;
      #pragma unroll
      for (int nb = 0; nb < 4; ++nb)
        #pragma unroll
        for (int r = 0; r < 4; ++r){
          float p = exp2f(sarr[nb][r] - mrun);
          sarr[nb][r] = p; rs += p;
        }
      rs += __shfl_xor(rs, 16);
      rs += __shfl_xor(rs, 32);
      lrun += rs;

      // ---- pack P into mfma16 A-frags (row=lrow=q, k=quad*4+j)
      f16x4 pa[4];
      #pragma unroll
      for (int nb = 0; nb < 4; ++nb){
        pa[nb][0] = (f16)sarr[nb][0];
        pa[nb][1] = (f16)sarr[nb][1];
        pa[nb][2] = (f16)sarr[nb][2];
        pa[nb][3] = (f16)sarr[nb][3];
      }

      // ---- O += P V : chained 16x16x16 MFMAs, Vt b64 fragments (swizzled)
      #pragma unroll
      for (int nb = 0; nb < 4; ++nb){
        #pragma unroll
        for (int nbh = 0; nbh < 4; ++nbh){
          int hd = nbh * 16 + lrow;
          int s2 = ((nb * 2 + (quad >> 1)) ^ (hd >> 3)) & 7;
          f16x4 vf = *(const f16x4*)(Vt + hd * 72 + (s2 << 3) + ((quad & 1) << 2));
          o[nbh] = __builtin_amdgcn_mfma_f32_16x16x16f16(pa[nb], vf, o[nbh], 0, 0, 0);
        }
      }
    }
  }

  if (whole){
    #pragma unroll
    for (int r = 0; r < 4; ++r){
      float inv = 1.0f / __shfl(lrun, (quad << 2) | r);
      int qg2 = q0 + quad * 4 + r;
      #pragma unroll
      for (int nbh = 0; nbh < 4; ++nbh){
        int col = h * 64 + nbh * 16 + lrow;
        attn_out[((size_t)b * TT + qg2) * 1024 + col] = (f16)(o[nbh][r] * inv);
      }
    }
  } else {
    int slot = bh * 36 + slot_base(J) + ci;
    f16* Ob = Opart + (size_t)slot * 8192;   // [128 rows][64 hd]
    #pragma unroll
    for (int nbh = 0; nbh < 4; ++nbh)
      #pragma unroll
      for (int r = 0; r < 4; ++r)
        Ob[(w * 16 + quad * 4 + r) * 64 + nbh * 16 + lrow] = (f16)o[nbh][r];
    if (quad == 0){
      MLpart[(size_t)slot * 256 + w * 16 + lrow] = mrun;
      MLpart[(size_t)slot * 256 + 128 + w * 16 + lrow] = lrun;
    }
  }
}

// ---------------- combine 2..4 partial chunks for J>=4 (128-row slots) ----------------
__global__ __launch_bounds__(256) void combine_kernel(const f16* __restrict__ Opart,
                                                      const float* __restrict__ ML,
                                                      f16* __restrict__ attn_out){
  int J = blockIdx.x + 4;           // 4..15
  int bh = blockIdx.y;              // 0..31
  int nch = (J < 8) ? 2 : ((J < 12) ? 3 : 4);
  int slot0 = bh * 36 + slot_base(J);
  int t = threadIdx.x;
  int row = t >> 1;                 // 0..127
  int hd0 = (t & 1) << 5;           // 0 or 32

  float m[4], l[4];
  float M = -1e30f;
  #pragma unroll
  for (int c = 0; c < 4; ++c){
    if (c < nch){
      m[c] = ML[(size_t)(slot0 + c) * 256 + row];
      l[c] = ML[(size_t)(slot0 + c) * 256 + 128 + row];
      M = fmaxf(M, m[c]);
    } else { m[c] = -1e30f; l[c] = 0.f; }
  }
  float acc[32];
  #pragma unroll
  for (int i = 0; i < 32; ++i) acc[i] = 0.f;
  float L = 0.f;
  #pragma unroll
  for (int c = 0; c < 4; ++c){
    if (c < nch){
      float wgt = exp2f(m[c] - M);
      L += l[c] * wgt;
      const f16* O = Opart + (size_t)(slot0 + c) * 8192 + row * 64 + hd0;
      f16x8 a0 = *(const f16x8*)O,        a1 = *(const f16x8*)(O + 8);
      f16x8 a2 = *(const f16x8*)(O + 16), a3 = *(const f16x8*)(O + 24);
      #pragma unroll
      for (int i = 0; i < 8; ++i){
        acc[i]      += (float)a0[i] * wgt;
        acc[i + 8]  += (float)a1[i] * wgt;
        acc[i + 16] += (float)a2[i] * wgt;
        acc[i + 24] += (float)a3[i] * wgt;
      }
    }
  }
  float invL = 1.0f / L;
  f16 outv[32];
  #pragma unroll
  for (int i = 0; i < 32; ++i) outv[i] = (f16)(acc[i] * invL);
  int b = bh >> 4, h = bh & 15;
  int qg = J * 128 + row;
  f16* dst = attn_out + ((size_t)b * TT + qg) * 1024 + h * 64 + hd0;
  *(uint4*)dst = *(uint4*)&outv[0];
  *(uint4*)(dst + 8) = *(uint4*)&outv[8];
  *(uint4*)(dst + 16) = *(uint4*)&outv[16];
  *(uint4*)(dst + 24) = *(uint4*)&outv[24];
}

extern "C" void kernel_launch(void* const* d_in, const int* in_sizes, int n_in,
                              void* d_out, int out_size, void* d_ws, size_t ws_size,
                              hipStream_t stream){
  (void)in_sizes; (void)n_in; (void)out_size; (void)ws_size;
  const float* x_f32  = (const float*)d_in[0];
  const float* gadj   = (const float*)d_in[1];
  const int*   etype  = (const int*)d_in[2];
  const float* wqkv   = (const float*)d_in[3];
  const float* wproj  = (const float*)d_in[4];
  const float* adjb   = (const float*)d_in[5];
  const float* etab   = (const float*)d_in[6];

  // workspace layout (peak ~72.3 MB):
  //  [0,8)    x_f16, reused as attn_out
  //  [8,32)   qkv
  //  [32,38)  wqkvT (dead after qkv GEMM) -- aliased by Opart [32,50.9) (1152 x 8192 f16)
  //  [51,53)  wprojT
  //  [53,54.2) MLpart (1152 x 256 f32)
  //  [55,72.3) pbias (triangle-compressed u32 tiles, transposed fragment order)
  char* ws = (char*)d_ws;
  f16*     x_f16  = (f16*)(ws);
  f16*     qkv    = (f16*)(ws + (8u  << 20));
  f16*     wqkvT  = (f16*)(ws + (32u << 20));
  f16*     Opart  = (f16*)(ws + (32u << 20));
  f16*     wprojT = (f16*)(ws + (51u << 20));
  float*   MLpart = (float*)(ws + (53u << 20));
  uint32_t* pbias = (uint32_t*)(ws + (55u << 20));
  f16*     attn_o = x_f16;  // reuse

  cvt_f2h_kernel<<<4096, 256, 0, stream>>>((const float4*)x_f32, (uint2*)x_f16, 1048576);
  pack_bias_kernel<<<1056, 256, 0, stream>>>(gadj, etype, pbias);
  transpose_cvt_kernel<<<dim3(48, 16), 256, 0, stream>>>(wqkv, wqkvT, 1024, 3072);
  transpose_cvt_kernel<<<dim3(16, 16), 256, 0, stream>>>(wproj, wprojT, 1024, 1024);
  gemm_f16_kernel<128><<<dim3(24, 32), 256, 0, stream>>>(x_f16, wqkvT, qkv, 4096, 3072, 1024, 0);
  attn_kernel<<<1280, 512, 0, stream>>>(qkv, pbias, adjb, etab, attn_o, Opart, MLpart);
  combine_kernel<<<dim3(12, 32), 256, 0, stream>>>(Opart, MLpart, attn_o);
  gemm_f16_kernel<64><<<dim3(16, 32), 256, 0, stream>>>(attn_o, wprojT, d_out, 4096, 1024, 1024, 1);
}

// Round 10
// 270.691 us; speedup vs baseline: 1.0414x; 1.0381x over previous
//
#include <hip/hip_runtime.h>
#include <stdint.h>

#define TT 2048
#define HH 16
#define LOG2E 1.44269504089f

typedef _Float16 f16;
typedef __attribute__((ext_vector_type(8))) _Float16 f16x8;
typedef __attribute__((ext_vector_type(4))) _Float16 f16x4;
typedef __attribute__((ext_vector_type(4))) float f32x4;
typedef unsigned short ushort_t;

// async global->LDS, 16B per lane (GEMM only)
__device__ __forceinline__ void gl_lds16(const void* g, void* l){
  __builtin_amdgcn_global_load_lds(
      (__attribute__((address_space(1))) void*)(void*)g,
      (__attribute__((address_space(3))) void*)l, 16, 0, 0);
}

// barrier WITHOUT vmcnt drain: LDS ops done, but global loads stay in flight
__device__ __forceinline__ void lds_barrier(){
  __asm__ volatile("s_waitcnt lgkmcnt(0)\n\ts_barrier" ::: "memory");
}

// ---------------- block schedule (chunk = 8 k-tiles), LPT order ----------------
struct SchedT { unsigned short v[80]; };
static constexpr SchedT make_sched(){
  SchedT s{};
  int idx = 0;
  for (int size = 8; size >= 1; --size){
    for (int qt = 31; qt >= 8; --qt){
      int full = qt >> 3;
      int tail = (qt & 7) + 1;
      if (size == 8)
        for (int ci = 0; ci < full; ++ci)
          s.v[idx++] = (unsigned short)(qt | (ci << 8));
      if (tail == size)
        s.v[idx++] = (unsigned short)(qt | (full << 8));
    }
    s.v[idx++] = (unsigned short)(size - 1);
  }
  return s;
}
__constant__ SchedT SCHED = make_sched();

// prefix of partial-slot count: slots for qt' in [8, qt)
__device__ __forceinline__ int slot_base(int qt){
  return (qt < 16) ? 2 * (qt - 8)
       : (qt < 24) ? 16 + 3 * (qt - 16)
                   : 40 + 4 * (qt - 24);
}

// ---------------- convert x: f32 -> f16 ----------------
__global__ __launch_bounds__(256) void cvt_f2h_kernel(const float4* __restrict__ in,
                                                      uint2* __restrict__ out, int n4){
  int i = blockIdx.x * 256 + threadIdx.x;
  if (i >= n4) return;
  float4 v = in[i];
  union { f16 h[4]; uint2 u; } o;
  o.h[0] = (f16)v.x; o.h[1] = (f16)v.y; o.h[2] = (f16)v.z; o.h[3] = (f16)v.w;
  out[i] = o.u;
}

// ---------------- pack bias: lower-triangle 64x64 tiles, TRANSPOSED frag order ----
// Consumer (swapped-QK^T attn): slot index = (q>>4)*64 + ((k>>2)&3)*16 + (q&15),
// word j=(k>>4)*4 + (k&3) holds element (q, k): u32 = f16(gadj) | etype<<16.
__global__ __launch_bounds__(256) void pack_bias_kernel(const float* __restrict__ gadj,
                                                        const int* __restrict__ etype,
                                                        uint32_t* __restrict__ out){
  int bid = blockIdx.x;
  int b = bid / 528, ti = bid - b * 528;
  int qt = (int)((sqrtf(8.f * (float)ti + 1.f) - 1.f) * 0.5f);
  while ((qt + 1) * (qt + 2) / 2 <= ti) ++qt;
  while (qt * (qt + 1) / 2 > ti) --qt;
  int kt = ti - qt * (qt + 1) / 2;

  int t = threadIdx.x;
  int row = t >> 2, c0 = (t & 3) << 4;     // reads row, cols c0..c0+15
  size_t src = ((size_t)b * TT + qt * 64 + row) * TT + kt * 64 + c0;
  uint32_t* dst = out + (size_t)bid * 4096;
  int wq = (row >> 4) * 64 + (row & 15);
  #pragma unroll
  for (int v4 = 0; v4 < 4; ++v4){
    float4 g = *(const float4*)(gadj + src + v4 * 4);
    int4   e = *(const int4*)(etype + src + v4 * 4);
    union { f16 h; ushort_t u; } c;
    uint4 o;
    c.h = (f16)g.x; o.x = (uint32_t)c.u | ((uint32_t)e.x << 16);
    c.h = (f16)g.y; o.y = (uint32_t)c.u | ((uint32_t)e.y << 16);
    c.h = (f16)g.z; o.z = (uint32_t)c.u | ((uint32_t)e.z << 16);
    c.h = (f16)g.w; o.w = (uint32_t)c.u | ((uint32_t)e.w << 16);
    *(uint4*)(dst + (((size_t)(wq + v4 * 16)) << 4) + ((t & 3) << 2)) = o;
  }
}

// ---------------- transpose+convert: f32 [R][C] -> f16 [C][R] ----------------
__global__ __launch_bounds__(256) void transpose_cvt_kernel(const float* __restrict__ in,
                                                            f16* __restrict__ out, int R, int C){
  __shared__ float tile[64][65];
  int c0 = blockIdx.x * 64, r0 = blockIdx.y * 64;
  int t = threadIdx.x;
  int row = t >> 2, cs = (t & 3) << 4;
  const float4* src = (const float4*)(in + (size_t)(r0 + row) * C + c0 + cs);
  float4 a = src[0], b = src[1], c = src[2], d = src[3];
  float* tr = &tile[row][cs];
  tr[0]=a.x; tr[1]=a.y; tr[2]=a.z;  tr[3]=a.w;
  tr[4]=b.x; tr[5]=b.y; tr[6]=b.z;  tr[7]=b.w;
  tr[8]=c.x; tr[9]=c.y; tr[10]=c.z; tr[11]=c.w;
  tr[12]=d.x;tr[13]=d.y;tr[14]=d.z; tr[15]=d.w;
  __syncthreads();
  f16 tmp[16];
  #pragma unroll
  for (int j = 0; j < 16; ++j) tmp[j] = (f16)tile[cs + j][row];
  f16* dst = out + (size_t)(c0 + row) * R + r0 + cs;
  *(uint4*)dst = *(uint4*)&tmp[0];
  *(uint4*)(dst + 8) = *(uint4*)&tmp[8];
}

// ---------------- GEMM: C[M][N] = A[M][K] @ Bt[N][K]^T, tile 128 x BN ----------------
// XCD-swizzled block mapping (T1): nwg must be divisible by 8.
template<int BN>
__global__ __launch_bounds__(256) void gemm_f16_kernel(const f16* __restrict__ A,
                                                       const f16* __restrict__ Bt,
                                                       void* __restrict__ Cout,
                                                       int M, int N, int K, int out_f32){
  constexpr int WN = BN / 2;
  constexpr int NI = WN / 16;
  __shared__ __align__(16) f16 As[128 * 32];
  __shared__ __align__(16) f16 Bs[BN * 32];
  int t = threadIdx.x;
  int w = t >> 6, lane = t & 63;
  int wm = (w >> 1) * 64, wn = (w & 1) * WN;
  int lrow = lane & 15, quad = lane >> 4;

  // XCD-aware swizzle: consecutive swz (same XCD) share bm rows -> L2 reuse
  int id = blockIdx.y * gridDim.x + blockIdx.x;
  int cpx = (gridDim.x * gridDim.y) >> 3;
  int swz = (id & 7) * cpx + (id >> 3);
  int bm = swz / gridDim.x;
  int bn = swz - bm * gridDim.x;

  f32x4 acc[4][NI];
  for (int i = 0; i < 4; ++i)
    for (int j = 0; j < NI; ++j)
      for (int r = 0; r < 4; ++r) acc[i][j][r] = 0.f;

  const int nk = K >> 5;
  for (int kt = 0; kt < nk; ++kt){
    int k0 = kt << 5;
    __syncthreads();
    #pragma unroll
    for (int i = 0; i < 2; ++i){
      int c = (w << 7) + (i << 6) + lane;
      gl_lds16(A + (size_t)((bm << 7) + (c >> 2)) * K + k0 + ((c & 3) << 3),
               As + ((w << 7) + (i << 6)) * 8);
      if constexpr (BN == 128){
        gl_lds16(Bt + (size_t)((bn << 7) + (c >> 2)) * K + k0 + ((c & 3) << 3),
                 Bs + ((w << 7) + (i << 6)) * 8);
      }
    }
    if constexpr (BN == 64){
      int c = (w << 6) + lane;
      gl_lds16(Bt + (size_t)((bn << 6) + (c >> 2)) * K + k0 + ((c & 3) << 3),
               Bs + (w << 6) * 8);
    }
    __syncthreads();
    f16x8 af[4], bfr[NI];
    #pragma unroll
    for (int mi = 0; mi < 4; ++mi)
      af[mi] = *(const f16x8*)(As + (wm + mi * 16 + lrow) * 32 + quad * 8);
    #pragma unroll
    for (int ni = 0; ni < NI; ++ni)
      bfr[ni] = *(const f16x8*)(Bs + (wn + ni * 16 + lrow) * 32 + quad * 8);
    __builtin_amdgcn_s_setprio(1);
    #pragma unroll
    for (int mi = 0; mi < 4; ++mi)
      #pragma unroll
      for (int ni = 0; ni < NI; ++ni)
        acc[mi][ni] = __builtin_amdgcn_mfma_f32_16x16x32_f16(af[mi], bfr[ni], acc[mi][ni], 0, 0, 0);
    __builtin_amdgcn_s_setprio(0);
  }

  #pragma unroll
  for (int mi = 0; mi < 4; ++mi)
    #pragma unroll
    for (int ni = 0; ni < NI; ++ni)
      #pragma unroll
      for (int r = 0; r < 4; ++r){
        int row = (bm << 7) + wm + mi * 16 + quad * 4 + r;
        int col = bn * BN + wn + ni * 16 + lrow;
        float val = acc[mi][ni][r];
        if (out_f32) ((float*)Cout)[(size_t)row * N + col] = val;
        else         ((f16*)Cout)[(size_t)row * N + col] = (f16)val;
      }
}

// ---------------- fused causal graph attention: swapped QK^T, register-resident P ----
// Exact R8 structure (best measured: 72 us) + T5 setprio around MFMA clusters.
__global__ __launch_bounds__(256, 4) void attn_kernel(const f16* __restrict__ qkv,
                                                      const uint32_t* __restrict__ pbias,
                                                      const float* __restrict__ adj_bias,
                                                      const float* __restrict__ edge_table,
                                                      f16* __restrict__ attn_out,
                                                      f16* __restrict__ Opart,
                                                      float* __restrict__ MLpart){
  __shared__ __align__(16) f16 Ks[64 * 72];
  __shared__ __align__(16) f16 Vt[64 * 72];   // transposed [hd][key], xor-swizzled 16B blocks
  __shared__ float edge_lds[32 * 17];         // 32 replicas, stride 17

  int bx = blockIdx.x;
  int bh = bx & 31;
  int h = bh & 15, b = bh >> 4;
  int ej = SCHED.v[bx >> 5];
  int qt = ej & 31, ci = ej >> 8;
  int ksrt = ci << 3;
  int kend = min(qt, ksrt + 7);
  bool whole = (qt < 8);

  int t = threadIdx.x;
  int w = t >> 6, lane = t & 63;
  int lrow = lane & 15, quad = lane >> 4;

  for (int i = t; i < 544; i += 256)
    edge_lds[i] = edge_table[(i % 17) * HH + h] * LOG2E;
  float adjb = adj_bias[h] * LOG2E;
  int erep = (lane & 31) * 17;

  int q0 = qt * 64 + w * 16;
  const size_t qrow = ((size_t)b * TT + q0 + lrow) * 3072 + h * 64;
  f16x8 qf0 = *(const f16x8*)(qkv + qrow + quad * 8);
  f16x8 qf1 = *(const f16x8*)(qkv + qrow + 32 + quad * 8);

  f32x4 o[4];
  for (int i = 0; i < 4; ++i)
    for (int r = 0; r < 4; ++r) o[i][r] = 0.f;
  float mrun = -1e30f, lrun = 0.f;   // this lane's q = q0 + lrow

  // staging geometry: thread handles keys (keyA, keyA+1) x hd segment hdA..hdA+7
  const int keyA = (t >> 3) << 1;
  const int hdA  = (t & 7) << 3;
  const int sA   = ((keyA >> 3) ^ (hdA >> 3)) & 7;
  const f16* kbase = qkv + (size_t)b * TT * 3072 + 1024 + h * 64;
  const f16* vbase = qkv + (size_t)b * TT * 3072 + 2048 + h * 64;
  const size_t koffA = (size_t)keyA * 3072 + hdA;
  const size_t koffB = koffA + 3072;

  const float SCL = 0.125f * LOG2E;

  const int tribase = b * 528 + ((qt * (qt + 1)) >> 1);
  const uint32_t* bthread = pbias + ((size_t)t << 4);
  const int qg = q0 + lrow;          // this lane's global q row

  // ---- prefetch first tile's K/V
  uint4 ka, kb, va, vb;
  {
    const f16* kr = kbase + (size_t)(ksrt * 64) * 3072;
    const f16* vr = vbase + (size_t)(ksrt * 64) * 3072;
    ka = *(const uint4*)(kr + koffA); kb = *(const uint4*)(kr + koffB);
    va = *(const uint4*)(vr + koffA); vb = *(const uint4*)(vr + koffB);
  }

  for (int kt2 = ksrt; kt2 <= kend; ++kt2){
    lds_barrier();
    // ---- bias loads for CUR tile (consumed at mask step)
    union B4 { uint4 v; uint32_t e[4]; } bb0, bb1, bb2, bb3;
    {
      const uint32_t* tp = bthread + ((size_t)(tribase + kt2) << 12);
      bb0.v = *(const uint4*)(tp + 0);
      bb1.v = *(const uint4*)(tp + 4);
      bb2.v = *(const uint4*)(tp + 8);
      bb3.v = *(const uint4*)(tp + 12);
    }
    // ---- LDS writes from prefetched regs
    *(uint4*)(Ks + keyA * 72 + hdA) = ka;
    *(uint4*)(Ks + (keyA + 1) * 72 + hdA) = kb;
    {
      union { uint4 u; f16 hh[8]; } ua, ub;
      ua.u = va; ub.u = vb;
      #pragma unroll
      for (int jj = 0; jj < 8; ++jj){
        union { f16 h[2]; uint32_t wv; } pr;
        pr.h[0] = ua.hh[jj]; pr.h[1] = ub.hh[jj];
        *(uint32_t*)(Vt + (hdA + jj) * 72 + (sA << 3) + (keyA & 7)) = pr.wv;
      }
    }
    // ---- issue NEXT tile's K/V
    if (kt2 < kend){
      const f16* kr = kbase + (size_t)((kt2 + 1) * 64) * 3072;
      const f16* vr = vbase + (size_t)((kt2 + 1) * 64) * 3072;
      ka = *(const uint4*)(kr + koffA); kb = *(const uint4*)(kr + koffB);
      va = *(const uint4*)(vr + koffA); vb = *(const uint4*)(vr + koffB);
    }
    lds_barrier();

    // ---- S^T = K Q^T  (swapped operands; D: col=lrow=q, row=quad*4+r=k_local)
    f32x4 sf[4];
    __builtin_amdgcn_s_setprio(1);
    #pragma unroll
    for (int nb = 0; nb < 4; ++nb){
      f32x4 s = {0.f, 0.f, 0.f, 0.f};
      f16x8 kf0 = *(const f16x8*)(Ks + (nb * 16 + lrow) * 72 + quad * 8);
      f16x8 kf1 = *(const f16x8*)(Ks + (nb * 16 + lrow) * 72 + 32 + quad * 8);
      s = __builtin_amdgcn_mfma_f32_16x16x32_f16(kf0, qf0, s, 0, 0, 0);
      s = __builtin_amdgcn_mfma_f32_16x16x32_f16(kf1, qf1, s, 0, 0, 0);
      sf[nb] = s;
    }
    __builtin_amdgcn_s_setprio(0);

    // ---- bias + causal mask: lane holds (q=qg, k = kt2*64 + nb*16 + quad*4 + r)
    int kq = kt2 * 64 + quad * 4;
    float sarr[4][4];
    bool diag = (kt2 == qt);
#define MASK_NB(nb, BB)                                                          \
    {                                                                            \
      _Pragma("unroll")                                                          \
      for (int r = 0; r < 4; ++r){                                               \
        float v;                                                                 \
        if (diag && (kq + nb * 16 + r > qg)) v = -1e30f;                         \
        else {                                                                   \
          uint32_t bp = BB.e[r];                                                 \
          union { ushort_t u; f16 h; } cv; cv.u = (ushort_t)bp;                  \
          v = sf[nb][r] * SCL + adjb * (float)cv.h + edge_lds[erep + (bp >> 16)];\
        }                                                                        \
        sarr[nb][r] = v;                                                         \
      }                                                                          \
    }
    MASK_NB(0, bb0)
    MASK_NB(1, bb1)
    MASK_NB(2, bb2)
    MASK_NB(3, bb3)
#undef MASK_NB

    // ---- online softmax: in-lane over 16 + cross-quad shfl (lanes l, l^16, l^32, l^48)
    float m_ = -1e30f;
    #pragma unroll
    for (int nb = 0; nb < 4; ++nb)
      #pragma unroll
      for (int r = 0; r < 4; ++r)
        m_ = fmaxf(m_, sarr[nb][r]);
    m_ = fmaxf(m_, __shfl_xor(m_, 16));
    m_ = fmaxf(m_, __shfl_xor(m_, 32));
    bool need = (m_ > mrun + 5.0f);
    if (__any(need)){
      float mnew = fmaxf(mrun, m_);
      float alpha = exp2f(mrun - mnew);
      lrun *= alpha;
      #pragma unroll
      for (int r = 0; r < 4; ++r){
        float ar = __shfl(alpha, (quad << 2) | r);   // alpha for q_local = quad*4+r
        #pragma unroll
        for (int nbh = 0; nbh < 4; ++nbh) o[nbh][r] *= ar;
      }
      mrun = mnew;
    }
    float rs = 0.f;
    #pragma unroll
    for (int nb = 0; nb < 4; ++nb)
      #pragma unroll
      for (int r = 0; r < 4; ++r){
        float p = exp2f(sarr[nb][r] - mrun);
        sarr[nb][r] = p; rs += p;
      }
    rs += __shfl_xor(rs, 16);
    rs += __shfl_xor(rs, 32);
    lrun += rs;

    // ---- pack P into mfma16 A-frags (layout match: row=lrow=q, k=quad*4+j)
    f16x4 pa[4];
    #pragma unroll
    for (int nb = 0; nb < 4; ++nb){
      pa[nb][0] = (f16)sarr[nb][0];
      pa[nb][1] = (f16)sarr[nb][1];
      pa[nb][2] = (f16)sarr[nb][2];
      pa[nb][3] = (f16)sarr[nb][3];
    }

    // ---- O += P V : chained 16x16x16 MFMAs, Vt b64 fragments (swizzled)
    __builtin_amdgcn_s_setprio(1);
    #pragma unroll
    for (int nb = 0; nb < 4; ++nb){
      #pragma unroll
      for (int nbh = 0; nbh < 4; ++nbh){
        int hd = nbh * 16 + lrow;
        int s2 = ((nb * 2 + (quad >> 1)) ^ (hd >> 3)) & 7;
        f16x4 vf = *(const f16x4*)(Vt + hd * 72 + (s2 << 3) + ((quad & 1) << 2));
        o[nbh] = __builtin_amdgcn_mfma_f32_16x16x16f16(pa[nb], vf, o[nbh], 0, 0, 0);
      }
    }
    __builtin_amdgcn_s_setprio(0);
  }

  if (whole){
    #pragma unroll
    for (int r = 0; r < 4; ++r){
      float inv = 1.0f / __shfl(lrun, (quad << 2) | r);
      int qg2 = q0 + quad * 4 + r;
      #pragma unroll
      for (int nbh = 0; nbh < 4; ++nbh){
        int col = h * 64 + nbh * 16 + lrow;
        attn_out[((size_t)b * TT + qg2) * 1024 + col] = (f16)(o[nbh][r] * inv);
      }
    }
  } else {
    int slot = bh * 72 + slot_base(qt) + ci;
    f16* Ob = Opart + (size_t)slot * 4096;
    #pragma unroll
    for (int nbh = 0; nbh < 4; ++nbh)
      #pragma unroll
      for (int r = 0; r < 4; ++r)
        Ob[(w * 16 + quad * 4 + r) * 64 + nbh * 16 + lrow] = (f16)o[nbh][r];
    if (quad == 0){
      MLpart[(size_t)slot * 128 + w * 16 + lrow] = mrun;
      MLpart[(size_t)slot * 128 + 64 + w * 16 + lrow] = lrun;
    }
  }
}

// ---------------- combine 2..4 partial chunks for qt>=8 ----------------
__global__ __launch_bounds__(256) void combine_kernel(const f16* __restrict__ Opart,
                                                      const float* __restrict__ ML,
                                                      f16* __restrict__ attn_out){
  int qt = blockIdx.x + 8;          // 8..31
  int bh = blockIdx.y;              // 0..31
  int nch = (qt >> 3) + 1;          // 2..4
  int slot0 = bh * 72 + slot_base(qt);
  int t = threadIdx.x;
  int q = t >> 2;
  int hd0 = (t & 3) << 4;

  float m[4], l[4];
  float M = -1e30f;
  #pragma unroll
  for (int c = 0; c < 4; ++c){
    if (c < nch){
      m[c] = ML[(size_t)(slot0 + c) * 128 + q];
      l[c] = ML[(size_t)(slot0 + c) * 128 + 64 + q];
      M = fmaxf(M, m[c]);
    } else { m[c] = -1e30f; l[c] = 0.f; }
  }
  float acc[16];
  #pragma unroll
  for (int i = 0; i < 16; ++i) acc[i] = 0.f;
  float L = 0.f;
  #pragma unroll
  for (int c = 0; c < 4; ++c){
    if (c < nch){
      float wgt = exp2f(m[c] - M);
      L += l[c] * wgt;
      const f16* O = Opart + (size_t)(slot0 + c) * 4096 + q * 64 + hd0;
      f16x8 a0 = *(const f16x8*)O, a1 = *(const f16x8*)(O + 8);
      #pragma unroll
      for (int i = 0; i < 8; ++i){
        acc[i]     += (float)a0[i] * wgt;
        acc[i + 8] += (float)a1[i] * wgt;
      }
    }
  }
  float invL = 1.0f / L;
  f16 outv[16];
  #pragma unroll
  for (int i = 0; i < 16; ++i) outv[i] = (f16)(acc[i] * invL);
  int b = bh >> 4, h = bh & 15;
  f16* dst = attn_out + ((size_t)b * TT + qt * 64 + q) * 1024 + h * 64 + hd0;
  *(uint4*)dst = *(uint4*)&outv[0];
  *(uint4*)(dst + 8) = *(uint4*)&outv[8];
}

extern "C" void kernel_launch(void* const* d_in, const int* in_sizes, int n_in,
                              void* d_out, int out_size, void* d_ws, size_t ws_size,
                              hipStream_t stream){
  (void)in_sizes; (void)n_in; (void)out_size; (void)ws_size;
  const float* x_f32  = (const float*)d_in[0];
  const float* gadj   = (const float*)d_in[1];
  const int*   etype  = (const int*)d_in[2];
  const float* wqkv   = (const float*)d_in[3];
  const float* wproj  = (const float*)d_in[4];
  const float* adjb   = (const float*)d_in[5];
  const float* etab   = (const float*)d_in[6];

  // workspace layout (peak ~72.3 MB):
  //  [0,8)    x_f16, reused as attn_out
  //  [8,32)   qkv
  //  [32,38)  wqkvT (dead after qkv GEMM) -- aliased by Opart [32,50.9)
  //  [51,53)  wprojT
  //  [53,54.2) MLpart
  //  [55,72.3) pbias (triangle-compressed u32 tiles, transposed fragment order)
  char* ws = (char*)d_ws;
  f16*     x_f16  = (f16*)(ws);
  f16*     qkv    = (f16*)(ws + (8u  << 20));
  f16*     wqkvT  = (f16*)(ws + (32u << 20));
  f16*     Opart  = (f16*)(ws + (32u << 20));
  f16*     wprojT = (f16*)(ws + (51u << 20));
  float*   MLpart = (float*)(ws + (53u << 20));
  uint32_t* pbias = (uint32_t*)(ws + (55u << 20));
  f16*     attn_o = x_f16;  // reuse

  cvt_f2h_kernel<<<4096, 256, 0, stream>>>((const float4*)x_f32, (uint2*)x_f16, 1048576);
  pack_bias_kernel<<<1056, 256, 0, stream>>>(gadj, etype, pbias);
  transpose_cvt_kernel<<<dim3(48, 16), 256, 0, stream>>>(wqkv, wqkvT, 1024, 3072);
  transpose_cvt_kernel<<<dim3(16, 16), 256, 0, stream>>>(wproj, wprojT, 1024, 1024);
  gemm_f16_kernel<128><<<dim3(24, 32), 256, 0, stream>>>(x_f16, wqkvT, qkv, 4096, 3072, 1024, 0);
  attn_kernel<<<2560, 256, 0, stream>>>(qkv, pbias, adjb, etab, attn_o, Opart, MLpart);
  combine_kernel<<<dim3(24, 32), 256, 0, stream>>>(Opart, MLpart, attn_o);
  gemm_f16_kernel<64><<<dim3(16, 32), 256, 0, stream>>>(attn_o, wprojT, d_out, 4096, 1024, 1024, 1);
}

// Round 11
// 263.837 us; speedup vs baseline: 1.0685x; 1.0260x over previous
//
#include <hip/hip_runtime.h>
#include <stdint.h>

#define TT 2048
#define HH 16
#define LOG2E 1.44269504089f

typedef _Float16 f16;
typedef __attribute__((ext_vector_type(8))) _Float16 f16x8;
typedef __attribute__((ext_vector_type(4))) _Float16 f16x4;
typedef __attribute__((ext_vector_type(4))) float f32x4;
typedef unsigned short ushort_t;

// async global->LDS, 16B per lane (GEMM only)
__device__ __forceinline__ void gl_lds16(const void* g, void* l){
  __builtin_amdgcn_global_load_lds(
      (__attribute__((address_space(1))) void*)(void*)g,
      (__attribute__((address_space(3))) void*)l, 16, 0, 0);
}

// barrier WITHOUT vmcnt drain: LDS ops done, but global loads stay in flight
__device__ __forceinline__ void lds_barrier(){
  __asm__ volatile("s_waitcnt lgkmcnt(0)\n\ts_barrier" ::: "memory");
}

// ---------------- block schedule (chunk = 8 k-tiles), LPT order ----------------
struct SchedT { unsigned short v[80]; };
static constexpr SchedT make_sched(){
  SchedT s{};
  int idx = 0;
  for (int size = 8; size >= 1; --size){
    for (int qt = 31; qt >= 8; --qt){
      int full = qt >> 3;
      int tail = (qt & 7) + 1;
      if (size == 8)
        for (int ci = 0; ci < full; ++ci)
          s.v[idx++] = (unsigned short)(qt | (ci << 8));
      if (tail == size)
        s.v[idx++] = (unsigned short)(qt | (full << 8));
    }
    s.v[idx++] = (unsigned short)(size - 1);
  }
  return s;
}
__constant__ SchedT SCHED = make_sched();

// prefix of partial-slot count: slots for qt' in [8, qt)
__device__ __forceinline__ int slot_base(int qt){
  return (qt < 16) ? 2 * (qt - 8)
       : (qt < 24) ? 16 + 3 * (qt - 16)
                   : 40 + 4 * (qt - 24);
}

// ---------------- fused prep: pack_bias + cvt_f2h + 2 transposes ----------------
// blocks [0,1056): pack_bias; [1056,5152): cvt; [5152,5920): wqkv^T; [5920,6176): wproj^T
__global__ __launch_bounds__(256) void prep_kernel(const float4* __restrict__ x_in,
                                                   uint2* __restrict__ x_out,
                                                   const float* __restrict__ gadj,
                                                   const int* __restrict__ etype,
                                                   uint32_t* __restrict__ pbias,
                                                   const float* __restrict__ wqkv,
                                                   f16* __restrict__ wqkvT,
                                                   const float* __restrict__ wproj,
                                                   f16* __restrict__ wprojT){
  __shared__ float tile[64][65];
  int bid = blockIdx.x;
  int t = threadIdx.x;

  if (bid < 1056){
    // ---- pack bias: lower-triangle 64x64 tiles, TRANSPOSED frag order
    // slot index = (q>>4)*64 + ((k>>2)&3)*16 + (q&15), word j=(k>>4)*4+(k&3):
    // u32 = f16(gadj) | etype<<16.
    int b = bid / 528, ti = bid - b * 528;
    int qt = (int)((sqrtf(8.f * (float)ti + 1.f) - 1.f) * 0.5f);
    while ((qt + 1) * (qt + 2) / 2 <= ti) ++qt;
    while (qt * (qt + 1) / 2 > ti) --qt;
    int kt = ti - qt * (qt + 1) / 2;

    int row = t >> 2, c0 = (t & 3) << 4;
    size_t src = ((size_t)b * TT + qt * 64 + row) * TT + kt * 64 + c0;
    uint32_t* dst = pbias + (size_t)bid * 4096;
    int wq = (row >> 4) * 64 + (row & 15);
    #pragma unroll
    for (int v4 = 0; v4 < 4; ++v4){
      float4 g = *(const float4*)(gadj + src + v4 * 4);
      int4   e = *(const int4*)(etype + src + v4 * 4);
      union { f16 h; ushort_t u; } c;
      uint4 o;
      c.h = (f16)g.x; o.x = (uint32_t)c.u | ((uint32_t)e.x << 16);
      c.h = (f16)g.y; o.y = (uint32_t)c.u | ((uint32_t)e.y << 16);
      c.h = (f16)g.z; o.z = (uint32_t)c.u | ((uint32_t)e.z << 16);
      c.h = (f16)g.w; o.w = (uint32_t)c.u | ((uint32_t)e.w << 16);
      *(uint4*)(dst + (((size_t)(wq + v4 * 16)) << 4) + ((t & 3) << 2)) = o;
    }
  } else if (bid < 5152){
    // ---- convert x: f32 -> f16
    int i = (bid - 1056) * 256 + t;
    float4 v = x_in[i];
    union { f16 h[4]; uint2 u; } o;
    o.h[0] = (f16)v.x; o.h[1] = (f16)v.y; o.h[2] = (f16)v.z; o.h[3] = (f16)v.w;
    x_out[i] = o.u;
  } else {
    // ---- transpose+convert: f32 [R][C] -> f16 [C][R]
    const float* in; f16* out; int R, C, bxx, byy;
    if (bid < 5920){
      int tb = bid - 5152; in = wqkv; out = wqkvT; R = 1024; C = 3072;
      bxx = tb % 48; byy = tb / 48;
    } else {
      int tb = bid - 5920; in = wproj; out = wprojT; R = 1024; C = 1024;
      bxx = tb & 15; byy = tb >> 4;
    }
    int c0 = bxx * 64, r0 = byy * 64;
    int row = t >> 2, cs = (t & 3) << 4;
    const float4* src = (const float4*)(in + (size_t)(r0 + row) * C + c0 + cs);
    float4 a = src[0], b = src[1], c = src[2], d = src[3];
    float* tr = &tile[row][cs];
    tr[0]=a.x; tr[1]=a.y; tr[2]=a.z;  tr[3]=a.w;
    tr[4]=b.x; tr[5]=b.y; tr[6]=b.z;  tr[7]=b.w;
    tr[8]=c.x; tr[9]=c.y; tr[10]=c.z; tr[11]=c.w;
    tr[12]=d.x;tr[13]=d.y;tr[14]=d.z; tr[15]=d.w;
    __syncthreads();
    f16 tmp[16];
    #pragma unroll
    for (int j = 0; j < 16; ++j) tmp[j] = (f16)tile[cs + j][row];
    f16* dst = out + (size_t)(c0 + row) * R + r0 + cs;
    *(uint4*)dst = *(uint4*)&tmp[0];
    *(uint4*)(dst + 8) = *(uint4*)&tmp[8];
  }
}

// ---------------- GEMM: C[M][N] = A[M][K] @ Bt[N][K]^T, tile 128 x BN ----------------
// XCD-swizzled block mapping (T1): nwg must be divisible by 8.
template<int BN>
__global__ __launch_bounds__(256) void gemm_f16_kernel(const f16* __restrict__ A,
                                                       const f16* __restrict__ Bt,
                                                       void* __restrict__ Cout,
                                                       int M, int N, int K, int out_f32){
  constexpr int WN = BN / 2;
  constexpr int NI = WN / 16;
  __shared__ __align__(16) f16 As[128 * 32];
  __shared__ __align__(16) f16 Bs[BN * 32];
  int t = threadIdx.x;
  int w = t >> 6, lane = t & 63;
  int wm = (w >> 1) * 64, wn = (w & 1) * WN;
  int lrow = lane & 15, quad = lane >> 4;

  // XCD-aware swizzle: consecutive swz (same XCD) share bm rows -> L2 reuse
  int id = blockIdx.y * gridDim.x + blockIdx.x;
  int cpx = (gridDim.x * gridDim.y) >> 3;
  int swz = (id & 7) * cpx + (id >> 3);
  int bm = swz / gridDim.x;
  int bn = swz - bm * gridDim.x;

  f32x4 acc[4][NI];
  for (int i = 0; i < 4; ++i)
    for (int j = 0; j < NI; ++j)
      for (int r = 0; r < 4; ++r) acc[i][j][r] = 0.f;

  const int nk = K >> 5;
  for (int kt = 0; kt < nk; ++kt){
    int k0 = kt << 5;
    __syncthreads();
    #pragma unroll
    for (int i = 0; i < 2; ++i){
      int c = (w << 7) + (i << 6) + lane;
      gl_lds16(A + (size_t)((bm << 7) + (c >> 2)) * K + k0 + ((c & 3) << 3),
               As + ((w << 7) + (i << 6)) * 8);
      if constexpr (BN == 128){
        gl_lds16(Bt + (size_t)((bn << 7) + (c >> 2)) * K + k0 + ((c & 3) << 3),
                 Bs + ((w << 7) + (i << 6)) * 8);
      }
    }
    if constexpr (BN == 64){
      int c = (w << 6) + lane;
      gl_lds16(Bt + (size_t)((bn << 6) + (c >> 2)) * K + k0 + ((c & 3) << 3),
               Bs + (w << 6) * 8);
    }
    __syncthreads();
    f16x8 af[4], bfr[NI];
    #pragma unroll
    for (int mi = 0; mi < 4; ++mi)
      af[mi] = *(const f16x8*)(As + (wm + mi * 16 + lrow) * 32 + quad * 8);
    #pragma unroll
    for (int ni = 0; ni < NI; ++ni)
      bfr[ni] = *(const f16x8*)(Bs + (wn + ni * 16 + lrow) * 32 + quad * 8);
    __builtin_amdgcn_s_setprio(1);
    #pragma unroll
    for (int mi = 0; mi < 4; ++mi)
      #pragma unroll
      for (int ni = 0; ni < NI; ++ni)
        acc[mi][ni] = __builtin_amdgcn_mfma_f32_16x16x32_f16(af[mi], bfr[ni], acc[mi][ni], 0, 0, 0);
    __builtin_amdgcn_s_setprio(0);
  }

  #pragma unroll
  for (int mi = 0; mi < 4; ++mi)
    #pragma unroll
    for (int ni = 0; ni < NI; ++ni)
      #pragma unroll
      for (int r = 0; r < 4; ++r){
        int row = (bm << 7) + wm + mi * 16 + quad * 4 + r;
        int col = bn * BN + wn + ni * 16 + lrow;
        float val = acc[mi][ni][r];
        if (out_f32) ((float*)Cout)[(size_t)row * N + col] = val;
        else         ((f16*)Cout)[(size_t)row * N + col] = (f16)val;
      }
}

// ---------------- fused causal graph attention: swapped QK^T, register-resident P ----
// R10 structure + XCD-grouped block remap: all 16 h-blocks of one (chunk,b) group
// land on the same XCD (bx%8) so their shared pbias tile stays in that XCD's L2.
__global__ __launch_bounds__(256, 4) void attn_kernel(const f16* __restrict__ qkv,
                                                      const uint32_t* __restrict__ pbias,
                                                      const float* __restrict__ adj_bias,
                                                      const float* __restrict__ edge_table,
                                                      f16* __restrict__ attn_out,
                                                      f16* __restrict__ Opart,
                                                      float* __restrict__ MLpart){
  __shared__ __align__(16) f16 Ks[64 * 72];
  __shared__ __align__(16) f16 Vt[64 * 72];   // transposed [hd][key], xor-swizzled 16B blocks
  __shared__ float edge_lds[32 * 17];         // 32 replicas, stride 17

  // XCD-grouped mapping: bx = (g&7) + 8*(h + 16*(g>>3)); g = chunk*2 + b
  int bxn = blockIdx.x;
  int xcd = bxn & 7;
  int rem = bxn >> 3;                 // 0..319
  int g   = xcd + ((rem >> 4) << 3);  // group 0..159, 16 members share an XCD
  int h   = rem & 15;
  int b   = g & 1;
  int bh  = b * 16 + h;
  int ej = SCHED.v[g >> 1];
  int qt = ej & 31, ci = ej >> 8;
  int ksrt = ci << 3;
  int kend = min(qt, ksrt + 7);
  bool whole = (qt < 8);

  int t = threadIdx.x;
  int w = t >> 6, lane = t & 63;
  int lrow = lane & 15, quad = lane >> 4;

  for (int i = t; i < 544; i += 256)
    edge_lds[i] = edge_table[(i % 17) * HH + h] * LOG2E;
  float adjb = adj_bias[h] * LOG2E;
  int erep = (lane & 31) * 17;

  int q0 = qt * 64 + w * 16;
  const size_t qrow = ((size_t)b * TT + q0 + lrow) * 3072 + h * 64;
  f16x8 qf0 = *(const f16x8*)(qkv + qrow + quad * 8);
  f16x8 qf1 = *(const f16x8*)(qkv + qrow + 32 + quad * 8);

  f32x4 o[4];
  for (int i = 0; i < 4; ++i)
    for (int r = 0; r < 4; ++r) o[i][r] = 0.f;
  float mrun = -1e30f, lrun = 0.f;   // this lane's q = q0 + lrow

  // staging geometry: thread handles keys (keyA, keyA+1) x hd segment hdA..hdA+7
  const int keyA = (t >> 3) << 1;
  const int hdA  = (t & 7) << 3;
  const int sA   = ((keyA >> 3) ^ (hdA >> 3)) & 7;
  const f16* kbase = qkv + (size_t)b * TT * 3072 + 1024 + h * 64;
  const f16* vbase = qkv + (size_t)b * TT * 3072 + 2048 + h * 64;
  const size_t koffA = (size_t)keyA * 3072 + hdA;
  const size_t koffB = koffA + 3072;

  const float SCL = 0.125f * LOG2E;

  const int tribase = b * 528 + ((qt * (qt + 1)) >> 1);
  const uint32_t* bthread = pbias + ((size_t)t << 4);
  const int qg = q0 + lrow;          // this lane's global q row

  // ---- prefetch first tile's K/V
  uint4 ka, kb, va, vb;
  {
    const f16* kr = kbase + (size_t)(ksrt * 64) * 3072;
    const f16* vr = vbase + (size_t)(ksrt * 64) * 3072;
    ka = *(const uint4*)(kr + koffA); kb = *(const uint4*)(kr + koffB);
    va = *(const uint4*)(vr + koffA); vb = *(const uint4*)(vr + koffB);
  }

  for (int kt2 = ksrt; kt2 <= kend; ++kt2){
    lds_barrier();
    // ---- bias loads for CUR tile (consumed at mask step)
    union B4 { uint4 v; uint32_t e[4]; } bb0, bb1, bb2, bb3;
    {
      const uint32_t* tp = bthread + ((size_t)(tribase + kt2) << 12);
      bb0.v = *(const uint4*)(tp + 0);
      bb1.v = *(const uint4*)(tp + 4);
      bb2.v = *(const uint4*)(tp + 8);
      bb3.v = *(const uint4*)(tp + 12);
    }
    // ---- LDS writes from prefetched regs
    *(uint4*)(Ks + keyA * 72 + hdA) = ka;
    *(uint4*)(Ks + (keyA + 1) * 72 + hdA) = kb;
    {
      union { uint4 u; f16 hh[8]; } ua, ub;
      ua.u = va; ub.u = vb;
      #pragma unroll
      for (int jj = 0; jj < 8; ++jj){
        union { f16 h[2]; uint32_t wv; } pr;
        pr.h[0] = ua.hh[jj]; pr.h[1] = ub.hh[jj];
        *(uint32_t*)(Vt + (hdA + jj) * 72 + (sA << 3) + (keyA & 7)) = pr.wv;
      }
    }
    // ---- issue NEXT tile's K/V
    if (kt2 < kend){
      const f16* kr = kbase + (size_t)((kt2 + 1) * 64) * 3072;
      const f16* vr = vbase + (size_t)((kt2 + 1) * 64) * 3072;
      ka = *(const uint4*)(kr + koffA); kb = *(const uint4*)(kr + koffB);
      va = *(const uint4*)(vr + koffA); vb = *(const uint4*)(vr + koffB);
    }
    lds_barrier();

    // ---- S^T = K Q^T  (swapped operands; D: col=lrow=q, row=quad*4+r=k_local)
    f32x4 sf[4];
    __builtin_amdgcn_s_setprio(1);
    #pragma unroll
    for (int nb = 0; nb < 4; ++nb){
      f32x4 s = {0.f, 0.f, 0.f, 0.f};
      f16x8 kf0 = *(const f16x8*)(Ks + (nb * 16 + lrow) * 72 + quad * 8);
      f16x8 kf1 = *(const f16x8*)(Ks + (nb * 16 + lrow) * 72 + 32 + quad * 8);
      s = __builtin_amdgcn_mfma_f32_16x16x32_f16(kf0, qf0, s, 0, 0, 0);
      s = __builtin_amdgcn_mfma_f32_16x16x32_f16(kf1, qf1, s, 0, 0, 0);
      sf[nb] = s;
    }
    __builtin_amdgcn_s_setprio(0);

    // ---- bias + causal mask: lane holds (q=qg, k = kt2*64 + nb*16 + quad*4 + r)
    int kq = kt2 * 64 + quad * 4;
    float sarr[4][4];
    bool diag = (kt2 == qt);
#define MASK_NB(nb, BB)                                                          \
    {                                                                            \
      _Pragma("unroll")                                                          \
      for (int r = 0; r < 4; ++r){                                               \
        float v;                                                                 \
        if (diag && (kq + nb * 16 + r > qg)) v = -1e30f;                         \
        else {                                                                   \
          uint32_t bp = BB.e[r];                                                 \
          union { ushort_t u; f16 h; } cv; cv.u = (ushort_t)bp;                  \
          v = sf[nb][r] * SCL + adjb * (float)cv.h + edge_lds[erep + (bp >> 16)];\
        }                                                                        \
        sarr[nb][r] = v;                                                         \
      }                                                                          \
    }
    MASK_NB(0, bb0)
    MASK_NB(1, bb1)
    MASK_NB(2, bb2)
    MASK_NB(3, bb3)
#undef MASK_NB

    // ---- online softmax: in-lane over 16 + cross-quad shfl (lanes l, l^16, l^32, l^48)
    float m_ = -1e30f;
    #pragma unroll
    for (int nb = 0; nb < 4; ++nb)
      #pragma unroll
      for (int r = 0; r < 4; ++r)
        m_ = fmaxf(m_, sarr[nb][r]);
    m_ = fmaxf(m_, __shfl_xor(m_, 16));
    m_ = fmaxf(m_, __shfl_xor(m_, 32));
    bool need = (m_ > mrun + 5.0f);
    if (__any(need)){
      float mnew = fmaxf(mrun, m_);
      float alpha = exp2f(mrun - mnew);
      lrun *= alpha;
      #pragma unroll
      for (int r = 0; r < 4; ++r){
        float ar = __shfl(alpha, (quad << 2) | r);   // alpha for q_local = quad*4+r
        #pragma unroll
        for (int nbh = 0; nbh < 4; ++nbh) o[nbh][r] *= ar;
      }
      mrun = mnew;
    }
    float rs = 0.f;
    #pragma unroll
    for (int nb = 0; nb < 4; ++nb)
      #pragma unroll
      for (int r = 0; r < 4; ++r){
        float p = exp2f(sarr[nb][r] - mrun);
        sarr[nb][r] = p; rs += p;
      }
    rs += __shfl_xor(rs, 16);
    rs += __shfl_xor(rs, 32);
    lrun += rs;

    // ---- pack P into mfma16 A-frags (layout match: row=lrow=q, k=quad*4+j)
    f16x4 pa[4];
    #pragma unroll
    for (int nb = 0; nb < 4; ++nb){
      pa[nb][0] = (f16)sarr[nb][0];
      pa[nb][1] = (f16)sarr[nb][1];
      pa[nb][2] = (f16)sarr[nb][2];
      pa[nb][3] = (f16)sarr[nb][3];
    }

    // ---- O += P V : chained 16x16x16 MFMAs, Vt b64 fragments (swizzled)
    __builtin_amdgcn_s_setprio(1);
    #pragma unroll
    for (int nb = 0; nb < 4; ++nb){
      #pragma unroll
      for (int nbh = 0; nbh < 4; ++nbh){
        int hd = nbh * 16 + lrow;
        int s2 = ((nb * 2 + (quad >> 1)) ^ (hd >> 3)) & 7;
        f16x4 vf = *(const f16x4*)(Vt + hd * 72 + (s2 << 3) + ((quad & 1) << 2));
        o[nbh] = __builtin_amdgcn_mfma_f32_16x16x16f16(pa[nb], vf, o[nbh], 0, 0, 0);
      }
    }
    __builtin_amdgcn_s_setprio(0);
  }

  if (whole){
    #pragma unroll
    for (int r = 0; r < 4; ++r){
      float inv = 1.0f / __shfl(lrun, (quad << 2) | r);
      int qg2 = q0 + quad * 4 + r;
      #pragma unroll
      for (int nbh = 0; nbh < 4; ++nbh){
        int col = h * 64 + nbh * 16 + lrow;
        attn_out[((size_t)b * TT + qg2) * 1024 + col] = (f16)(o[nbh][r] * inv);
      }
    }
  } else {
    int slot = bh * 72 + slot_base(qt) + ci;
    f16* Ob = Opart + (size_t)slot * 4096;
    #pragma unroll
    for (int nbh = 0; nbh < 4; ++nbh)
      #pragma unroll
      for (int r = 0; r < 4; ++r)
        Ob[(w * 16 + quad * 4 + r) * 64 + nbh * 16 + lrow] = (f16)o[nbh][r];
    if (quad == 0){
      MLpart[(size_t)slot * 128 + w * 16 + lrow] = mrun;
      MLpart[(size_t)slot * 128 + 64 + w * 16 + lrow] = lrun;
    }
  }
}

// ---------------- combine 2..4 partial chunks for qt>=8 ----------------
__global__ __launch_bounds__(256) void combine_kernel(const f16* __restrict__ Opart,
                                                      const float* __restrict__ ML,
                                                      f16* __restrict__ attn_out){
  int qt = blockIdx.x + 8;          // 8..31
  int bh = blockIdx.y;              // 0..31
  int nch = (qt >> 3) + 1;          // 2..4
  int slot0 = bh * 72 + slot_base(qt);
  int t = threadIdx.x;
  int q = t >> 2;
  int hd0 = (t & 3) << 4;

  float m[4], l[4];
  float M = -1e30f;
  #pragma unroll
  for (int c = 0; c < 4; ++c){
    if (c < nch){
      m[c] = ML[(size_t)(slot0 + c) * 128 + q];
      l[c] = ML[(size_t)(slot0 + c) * 128 + 64 + q];
      M = fmaxf(M, m[c]);
    } else { m[c] = -1e30f; l[c] = 0.f; }
  }
  float acc[16];
  #pragma unroll
  for (int i = 0; i < 16; ++i) acc[i] = 0.f;
  float L = 0.f;
  #pragma unroll
  for (int c = 0; c < 4; ++c){
    if (c < nch){
      float wgt = exp2f(m[c] - M);
      L += l[c] * wgt;
      const f16* O = Opart + (size_t)(slot0 + c) * 4096 + q * 64 + hd0;
      f16x8 a0 = *(const f16x8*)O, a1 = *(const f16x8*)(O + 8);
      #pragma unroll
      for (int i = 0; i < 8; ++i){
        acc[i]     += (float)a0[i] * wgt;
        acc[i + 8] += (float)a1[i] * wgt;
      }
    }
  }
  float invL = 1.0f / L;
  f16 outv[16];
  #pragma unroll
  for (int i = 0; i < 16; ++i) outv[i] = (f16)(acc[i] * invL);
  int b = bh >> 4, h = bh & 15;
  f16* dst = attn_out + ((size_t)b * TT + qt * 64 + q) * 1024 + h * 64 + hd0;
  *(uint4*)dst = *(uint4*)&outv[0];
  *(uint4*)(dst + 8) = *(uint4*)&outv[8];
}

extern "C" void kernel_launch(void* const* d_in, const int* in_sizes, int n_in,
                              void* d_out, int out_size, void* d_ws, size_t ws_size,
                              hipStream_t stream){
  (void)in_sizes; (void)n_in; (void)out_size; (void)ws_size;
  const float* x_f32  = (const float*)d_in[0];
  const float* gadj   = (const float*)d_in[1];
  const int*   etype  = (const int*)d_in[2];
  const float* wqkv   = (const float*)d_in[3];
  const float* wproj  = (const float*)d_in[4];
  const float* adjb   = (const float*)d_in[5];
  const float* etab   = (const float*)d_in[6];

  // workspace layout (peak ~72.3 MB):
  //  [0,8)    x_f16, reused as attn_out
  //  [8,32)   qkv
  //  [32,38)  wqkvT (dead after qkv GEMM) -- aliased by Opart [32,50.9)
  //  [51,53)  wprojT
  //  [53,54.2) MLpart
  //  [55,72.3) pbias (triangle-compressed u32 tiles, transposed fragment order)
  char* ws = (char*)d_ws;
  f16*     x_f16  = (f16*)(ws);
  f16*     qkv    = (f16*)(ws + (8u  << 20));
  f16*     wqkvT  = (f16*)(ws + (32u << 20));
  f16*     Opart  = (f16*)(ws + (32u << 20));
  f16*     wprojT = (f16*)(ws + (51u << 20));
  float*   MLpart = (float*)(ws + (53u << 20));
  uint32_t* pbias = (uint32_t*)(ws + (55u << 20));
  f16*     attn_o = x_f16;  // reuse

  prep_kernel<<<6176, 256, 0, stream>>>((const float4*)x_f32, (uint2*)x_f16,
                                        gadj, etype, pbias,
                                        wqkv, wqkvT, wproj, wprojT);
  gemm_f16_kernel<128><<<dim3(24, 32), 256, 0, stream>>>(x_f16, wqkvT, qkv, 4096, 3072, 1024, 0);
  attn_kernel<<<2560, 256, 0, stream>>>(qkv, pbias, adjb, etab, attn_o, Opart, MLpart);
  combine_kernel<<<dim3(24, 32), 256, 0, stream>>>(Opart, MLpart, attn_o);
  gemm_f16_kernel<64><<<dim3(16, 32), 256, 0, stream>>>(attn_o, wprojT, d_out, 4096, 1024, 1024, 1);
}